// Round 7
// baseline (478.080 us; speedup 1.0000x reference)
//
#include <hip/hip_runtime.h>
#include <hip/hip_bf16.h>

#define N_NODES 50000
#define N_EDGES 800000
#define N_GRAPHS 512
#define CAP 48   // 3 tiles of 16; P(deg>48) ~ 5e-11 for Poisson(16)

typedef __attribute__((ext_vector_type(8))) short short8v;   // 8 bf16
typedef __attribute__((ext_vector_type(4))) float f32x4;

__device__ inline float bf2f(unsigned short u) {
    union { unsigned int i; float f; } v; v.i = ((unsigned int)u) << 16; return v.f;
}
__device__ inline short f2bf(float f) {
    __hip_bfloat16 h = __float2bfloat16(f);
    return *reinterpret_cast<short*>(&h);
}

// ---------------------------------------------------------------------------
// Build bucketed CSR by dst, packing (eid, src) together. deg pre-zeroed.
// Pad slots keep garbage; readers clamp indices and mask contributions.
// ---------------------------------------------------------------------------
__global__ __launch_bounds__(256) void fill_csr(
    const int* __restrict__ dst, const int* __restrict__ src,
    int* __restrict__ deg, int2* __restrict__ ecsr)
{
    int e = blockIdx.x * blockDim.x + threadIdx.x;
    if (e < N_EDGES) {
        int d = dst[e];
        int slot = atomicAdd(&deg[d], 1);
        if (slot < CAP) ecsr[d * CAP + slot] = make_int2(e, src[e]);
    }
}

// fp32 -> bf16 bulk convert, 8 elems/thread
__global__ __launch_bounds__(256) void cvt_bf16_kernel(
    const float* __restrict__ in, unsigned short* __restrict__ out, int n8)
{
    int i = blockIdx.x * blockDim.x + threadIdx.x;
    if (i < n8) {
        const float4 a = ((const float4*)in)[2 * i];
        const float4 b = ((const float4*)in)[2 * i + 1];
        short8v o;
        o[0] = f2bf(a.x); o[1] = f2bf(a.y); o[2] = f2bf(a.z); o[3] = f2bf(a.w);
        o[4] = f2bf(b.x); o[5] = f2bf(b.y); o[6] = f2bf(b.z); o[7] = f2bf(b.w);
        ((short8v*)out)[i] = o;
    }
}

// ---------------------------------------------------------------------------
// Persistent-wave MFMA gather (bf16 node features in, bf16 hpre out):
//   hpre[n][:] = bf16( hin[n][:] + sum_e relu(hin[src[e]][:] + ea[e]@We + be) )
// B fragments (We rows + bias row at k=16, A[k=16]=1) built once per wave.
// Packed int2 CSR: lanes 0-15 load (eid,src), __shfl distributes -> no
// dependent src[] lookup. Plain stores, no atomics.
// ---------------------------------------------------------------------------
template <int DIN, bool EA16>
__global__ __launch_bounds__(256, 8) void gather_v4(
    const unsigned short* __restrict__ hin,  // [N,DIN] bf16
    const void* __restrict__ ea_v,           // [E,16] fp32 or bf16
    const int* __restrict__ deg,
    const int2* __restrict__ ecsr,           // [N,CAP] (eid, src)
    const float* __restrict__ We,            // [16,DIN] fp32
    const float* __restrict__ be,            // [DIN]
    unsigned short* __restrict__ hpre)       // [N,DIN] bf16 out
{
    constexpr int NB = DIN / 16;
    const float* eaf = (const float*)ea_v;
    const unsigned short* ea16 = (const unsigned short*)ea_v;

    const int lane = threadIdx.x & 63;
    const int col = lane & 15;   // A row (edge slot) AND output dim-in-block
    const int grp = lane >> 4;   // 0..3
    const int gwave = (blockIdx.x * blockDim.x + threadIdx.x) >> 6;
    const int nwaves = (gridDim.x * blockDim.x) >> 6;

    // --- B fragments, built once: We rows k=grp*8+j (grp<2); bias at k=16 ---
    short8v Bf[NB];
#pragma unroll
    for (int b = 0; b < NB; ++b) {
        short8v f = {};
        if (grp < 2) {
#pragma unroll
            for (int j = 0; j < 8; ++j)
                f[j] = f2bf(We[(grp * 8 + j) * DIN + b * 16 + col]);
        } else if (grp == 2) {
            f[0] = f2bf(be[b * 16 + col]);   // k=16 row = bias
        }
        Bf[b] = f;
    }

    for (int n = gwave; n < N_NODES; n += nwaves) {
        const int dgc = min(deg[n], CAP);
        const int nch = (dgc + 15) >> 4;

        float accv[NB];
#pragma unroll
        for (int b = 0; b < NB; ++b) accv[b] = 0.0f;

        for (int c = 0; c < nch; ++c) {
            const int base = n * CAP + c * 16;
            const int vc = dgc - c * 16;   // valid edges in this chunk (1..16)

            // lanes 0-15: one 8B load covers eid AND src (clamped vs garbage)
            int e_l = 0, s_l = 0;
            if (lane < 16) {
                const int2 p = ecsr[base + lane];
                e_l = min(max(p.x, 0), N_EDGES - 1);
                s_l = min(max(p.y, 0), N_NODES - 1);
            }

            // A fragment: row=col -> edge id held by lane col
            const int e_col = __shfl(e_l, col);
            short8v Af = {};
            if (grp < 2) {
                if (EA16) {
                    Af = *(const short8v*)(ea16 + (size_t)e_col * 16 + grp * 8);
                } else {
                    const float* ap = eaf + (size_t)e_col * 16 + grp * 8;
                    const float4 a0 = *(const float4*)(ap);
                    const float4 a1 = *(const float4*)(ap + 4);
                    Af[0] = f2bf(a0.x); Af[1] = f2bf(a0.y);
                    Af[2] = f2bf(a0.z); Af[3] = f2bf(a0.w);
                    Af[4] = f2bf(a1.x); Af[5] = f2bf(a1.y);
                    Af[6] = f2bf(a1.z); Af[7] = f2bf(a1.w);
                }
            } else if (grp == 2) {
                Af[0] = (short)0x3F80;   // bf16 1.0 -> picks up bias row
            }

            // src ids for this lane's 4 output rows (edges 4*grp+r)
            int sid[4];
            float msk[4];
#pragma unroll
            for (int r = 0; r < 4; ++r) {
                sid[r] = __shfl(s_l, 4 * grp + r);
                msk[r] = (4 * grp + r) < vc ? 1.0f : 0.0f;
            }

#pragma unroll
            for (int b = 0; b < NB; ++b) {
                const f32x4 zero = {0.0f, 0.0f, 0.0f, 0.0f};
                f32x4 lin = __builtin_amdgcn_mfma_f32_16x16x32_bf16(Af, Bf[b], zero, 0, 0, 0);
                float part = 0.0f;
#pragma unroll
                for (int r = 0; r < 4; ++r) {
                    const float x = bf2f(hin[(size_t)sid[r] * DIN + b * 16 + col]);
                    part = fmaf(msk[r], fmaxf(x + lin[r], 0.0f), part);
                }
                part += __shfl_xor(part, 16);
                part += __shfl_xor(part, 32);
                accv[b] += part;
            }
        }

        // self term + store (fused h = x + agg), bf16 out
#pragma unroll
        for (int b = 0; b < NB; ++b) {
            if (lane < 16) {
                const float self = bf2f(hin[(size_t)n * DIN + b * 16 + lane]);
                hpre[(size_t)n * DIN + b * 16 + lane] =
                    (unsigned short)f2bf(self + accv[b]);
            }
        }
    }
}

// ---------------------------------------------------------------------------
// Tiled GIN MLP (bf16 input): v = relu( relu(h@Wa+ba) @ Wb + bb )
// 32 nodes/block, 256 threads. MODE 0: write v bf16. MODE 1: run-length pool.
// ---------------------------------------------------------------------------
template <int DIN, int MODE>
__global__ __launch_bounds__(256) void mlp_kernel(
    const unsigned short* __restrict__ hpre,  // [N, DIN] bf16
    const float* __restrict__ Wa,     // [DIN,128]
    const float* __restrict__ ba,
    const float* __restrict__ Wb,     // [128,128]
    const float* __restrict__ bb,
    __hip_bfloat16* __restrict__ h1out,  // MODE 0
    const int* __restrict__ batch,       // MODE 1
    float* __restrict__ pooled)          // MODE 1 (pre-zeroed)
{
    constexpr int TN = 32;
    constexpr int PAD = 4;
    __shared__ float sh[TN][DIN + PAD];
    __shared__ float su[TN][128 + PAD];

    const int n0 = blockIdx.x * TN;
    const int tid = threadIdx.x;

    constexpr int TOT = TN * DIN;
    for (int f = tid * 4; f < TOT; f += 256 * 4) {
        const int row = f / DIN, colc = f % DIN;
        const int n = n0 + row;
        float4 v = make_float4(0.f, 0.f, 0.f, 0.f);
        if (n < N_NODES) {
            const ushort4 u = *(const ushort4*)(hpre + (size_t)n * DIN + colc);
            v.x = bf2f(u.x); v.y = bf2f(u.y);
            v.z = bf2f(u.z); v.w = bf2f(u.w);
        }
        *(float4*)&sh[row][colc] = v;
    }
    __syncthreads();

    const int g = tid & 31;
    const int qb = (tid >> 5) * 4;

    float acc[4][4];
#pragma unroll
    for (int q = 0; q < 4; ++q)
#pragma unroll
        for (int j = 0; j < 4; ++j) acc[q][j] = 0.0f;

    for (int k = 0; k < DIN; ++k) {
        const float4 w = *(const float4*)(Wa + (size_t)k * 128 + g * 4);
        const float h0 = sh[qb + 0][k], h1v = sh[qb + 1][k],
                    h2 = sh[qb + 2][k], h3 = sh[qb + 3][k];
        acc[0][0] = fmaf(h0, w.x, acc[0][0]); acc[0][1] = fmaf(h0, w.y, acc[0][1]);
        acc[0][2] = fmaf(h0, w.z, acc[0][2]); acc[0][3] = fmaf(h0, w.w, acc[0][3]);
        acc[1][0] = fmaf(h1v, w.x, acc[1][0]); acc[1][1] = fmaf(h1v, w.y, acc[1][1]);
        acc[1][2] = fmaf(h1v, w.z, acc[1][2]); acc[1][3] = fmaf(h1v, w.w, acc[1][3]);
        acc[2][0] = fmaf(h2, w.x, acc[2][0]); acc[2][1] = fmaf(h2, w.y, acc[2][1]);
        acc[2][2] = fmaf(h2, w.z, acc[2][2]); acc[2][3] = fmaf(h2, w.w, acc[2][3]);
        acc[3][0] = fmaf(h3, w.x, acc[3][0]); acc[3][1] = fmaf(h3, w.y, acc[3][1]);
        acc[3][2] = fmaf(h3, w.z, acc[3][2]); acc[3][3] = fmaf(h3, w.w, acc[3][3]);
    }

    const float4 bav = *(const float4*)(ba + g * 4);
#pragma unroll
    for (int q = 0; q < 4; ++q) {
        float4 u;
        u.x = fmaxf(acc[q][0] + bav.x, 0.f);
        u.y = fmaxf(acc[q][1] + bav.y, 0.f);
        u.z = fmaxf(acc[q][2] + bav.z, 0.f);
        u.w = fmaxf(acc[q][3] + bav.w, 0.f);
        *(float4*)&su[qb + q][g * 4] = u;
    }
    __syncthreads();

#pragma unroll
    for (int q = 0; q < 4; ++q)
#pragma unroll
        for (int j = 0; j < 4; ++j) acc[q][j] = 0.0f;

    for (int k = 0; k < 128; ++k) {
        const float4 w = *(const float4*)(Wb + (size_t)k * 128 + g * 4);
        const float u0 = su[qb + 0][k], u1 = su[qb + 1][k],
                    u2 = su[qb + 2][k], u3 = su[qb + 3][k];
        acc[0][0] = fmaf(u0, w.x, acc[0][0]); acc[0][1] = fmaf(u0, w.y, acc[0][1]);
        acc[0][2] = fmaf(u0, w.z, acc[0][2]); acc[0][3] = fmaf(u0, w.w, acc[0][3]);
        acc[1][0] = fmaf(u1, w.x, acc[1][0]); acc[1][1] = fmaf(u1, w.y, acc[1][1]);
        acc[1][2] = fmaf(u1, w.z, acc[1][2]); acc[1][3] = fmaf(u1, w.w, acc[1][3]);
        acc[2][0] = fmaf(u2, w.x, acc[2][0]); acc[2][1] = fmaf(u2, w.y, acc[2][1]);
        acc[2][2] = fmaf(u2, w.z, acc[2][2]); acc[2][3] = fmaf(u2, w.w, acc[2][3]);
        acc[3][0] = fmaf(u3, w.x, acc[3][0]); acc[3][1] = fmaf(u3, w.y, acc[3][1]);
        acc[3][2] = fmaf(u3, w.z, acc[3][2]); acc[3][3] = fmaf(u3, w.w, acc[3][3]);
    }

    const float4 bbv = *(const float4*)(bb + g * 4);

    if (MODE == 0) {
#pragma unroll
        for (int q = 0; q < 4; ++q) {
            const int n = n0 + qb + q;
            if (n < N_NODES) {
                float v0 = fmaxf(acc[q][0] + bbv.x, 0.f);
                float v1 = fmaxf(acc[q][1] + bbv.y, 0.f);
                float v2 = fmaxf(acc[q][2] + bbv.z, 0.f);
                float v3 = fmaxf(acc[q][3] + bbv.w, 0.f);
                ushort4 o;
                o.x = (unsigned short)f2bf(v0); o.y = (unsigned short)f2bf(v1);
                o.z = (unsigned short)f2bf(v2); o.w = (unsigned short)f2bf(v3);
                *(ushort4*)&h1out[(size_t)n * 128 + g * 4] = o;
            }
        }
    } else {
#pragma unroll
        for (int q = 0; q < 4; ++q) {
            float4 v;
            v.x = fmaxf(acc[q][0] + bbv.x, 0.f);
            v.y = fmaxf(acc[q][1] + bbv.y, 0.f);
            v.z = fmaxf(acc[q][2] + bbv.z, 0.f);
            v.w = fmaxf(acc[q][3] + bbv.w, 0.f);
            *(float4*)&sh[qb + q][g * 4] = v;
        }
        __syncthreads();
        if (tid < 128) {
            const int d = tid;
            const int lim = min(TN, N_NODES - n0);
            float s = 0.0f;
            int bprev = -1;
            for (int q = 0; q < lim; ++q) {
                const int b = batch[n0 + q];
                if (b != bprev) {
                    if (bprev >= 0) atomicAdd(&pooled[bprev * 128 + d], s);
                    s = 0.0f;
                    bprev = b;
                }
                s += sh[q][d];
            }
            if (bprev >= 0) atomicAdd(&pooled[bprev * 128 + d], s);
        }
    }
}

// ---------------------------------------------------------------------------
// Final FC
// ---------------------------------------------------------------------------
__global__ __launch_bounds__(128) void fc_kernel(
    const float* __restrict__ pooled,
    const float* __restrict__ Wfc,
    const float* __restrict__ bfc,
    float* __restrict__ out)
{
    const int g = blockIdx.x;
    const int d = threadIdx.x;
    __shared__ float sp[128];
    sp[d] = pooled[g * 128 + d];
    __syncthreads();
    float acc = bfc[d];
    for (int k = 0; k < 128; ++k) acc = fmaf(sp[k], Wfc[k * 128 + d], acc);
    out[g * 128 + d] = acc;
}

extern "C" void kernel_launch(void* const* d_in, const int* in_sizes, int n_in,
                              void* d_out, int out_size, void* d_ws, size_t ws_size,
                              hipStream_t stream) {
    const float* x    = (const float*)d_in[0];
    const int*   eidx = (const int*)d_in[1];
    const float* ea   = (const float*)d_in[2];
    const int*   batch= (const int*)d_in[3];
    const float* We1  = (const float*)d_in[4];
    const float* be1  = (const float*)d_in[5];
    const float* W1a  = (const float*)d_in[6];
    const float* b1a  = (const float*)d_in[7];
    const float* W1b  = (const float*)d_in[8];
    const float* b1b  = (const float*)d_in[9];
    const float* We2  = (const float*)d_in[10];
    const float* be2  = (const float*)d_in[11];
    const float* W2a  = (const float*)d_in[12];
    const float* b2a  = (const float*)d_in[13];
    const float* W2b  = (const float*)d_in[14];
    const float* b2b  = (const float*)d_in[15];
    const float* Wfc  = (const float*)d_in[16];
    const float* bfc  = (const float*)d_in[17];
    float* out = (float*)d_out;

    const int* srcp = eidx;
    const int* dstp = eidx + N_EDGES;

    // workspace: base 45.3 MB (x16 aliases h1); +25.6 MB ea16 if ws allows
    char* w = (char*)d_ws;
    unsigned short* hpre = (unsigned short*)w;  w += (size_t)N_NODES * 128 * 2;
    unsigned short* h1 = (unsigned short*)w;    w += (size_t)N_NODES * 128 * 2;
    int* deg  = (int*)w;                        w += (size_t)N_NODES * 4;
    int2* ecsr = (int2*)w;                      w += (size_t)N_NODES * CAP * 8;
    float* pooled = (float*)w;                  w += (size_t)N_GRAPHS * 128 * 4;
    unsigned short* ea16 = (unsigned short*)w;  // optional, 25.6 MB

    // x16 (9.6 MB) aliases h1's buffer (12.8 MB): dead once mlp1 writes h1.
    unsigned short* x16 = h1;

    const bool use_ea16 =
        ws_size >= (size_t)(w - (char*)d_ws) + (size_t)N_EDGES * 16 * 2;

    // ---- prep: CSR (packed eid+src) and bf16 conversions ----
    hipMemsetAsync(deg, 0, (size_t)N_NODES * 4, stream);
    fill_csr<<<(N_EDGES + 255) / 256, 256, 0, stream>>>(dstp, srcp, deg, ecsr);
    {
        const int n8 = N_NODES * 96 / 8;
        cvt_bf16_kernel<<<(n8 + 255) / 256, 256, 0, stream>>>(x, x16, n8);
    }
    if (use_ea16) {
        const int n8 = N_EDGES * 16 / 8;
        cvt_bf16_kernel<<<(n8 + 255) / 256, 256, 0, stream>>>(ea, ea16, n8);
    }

    const int gblocks = 2048;   // 8192 persistent waves (8/SIMD)

    // ---- layer 1 ----
    if (use_ea16)
        gather_v4<96, true><<<gblocks, 256, 0, stream>>>(
            x16, ea16, deg, ecsr, We1, be1, hpre);
    else
        gather_v4<96, false><<<gblocks, 256, 0, stream>>>(
            x16, ea, deg, ecsr, We1, be1, hpre);
    mlp_kernel<96, 0><<<(N_NODES + 31) / 32, 256, 0, stream>>>(
        hpre, W1a, b1a, W1b, b1b, (__hip_bfloat16*)h1, nullptr, nullptr);

    // ---- layer 2 ----
    if (use_ea16)
        gather_v4<128, true><<<gblocks, 256, 0, stream>>>(
            h1, ea16, deg, ecsr, We2, be2, hpre);
    else
        gather_v4<128, false><<<gblocks, 256, 0, stream>>>(
            h1, ea, deg, ecsr, We2, be2, hpre);
    hipMemsetAsync(pooled, 0, (size_t)N_GRAPHS * 128 * 4, stream);
    mlp_kernel<128, 1><<<(N_NODES + 31) / 32, 256, 0, stream>>>(
        hpre, W2a, b2a, W2b, b2b, nullptr, batch, pooled);

    // ---- readout ----
    fc_kernel<<<N_GRAPHS, 128, 0, stream>>>(pooled, Wfc, bfc, out);
}

// Round 8
// 462.009 us; speedup vs baseline: 1.0348x; 1.0348x over previous
//
#include <hip/hip_runtime.h>
#include <hip/hip_bf16.h>

#define N_NODES 50000
#define N_EDGES 800000
#define N_GRAPHS 512
#define CAP 48   // 3 tiles of 16; P(deg>48) ~ 5e-11 for Poisson(16)

typedef __attribute__((ext_vector_type(8))) short short8v;   // 8 bf16
typedef __attribute__((ext_vector_type(4))) float f32x4;

__device__ inline float bf2f(unsigned short u) {
    union { unsigned int i; float f; } v; v.i = ((unsigned int)u) << 16; return v.f;
}
__device__ inline short f2bf(float f) {
    __hip_bfloat16 h = __float2bfloat16(f);
    return *reinterpret_cast<short*>(&h);
}

// ---------------------------------------------------------------------------
// PERMUTED bf16 row layout (per node row of D dims, D%32==0):
//   memory position m = 32*p + 2*c + half  <->  dim d = 32*p + 16*half + c
// so dims (32p+c, 32p+16+c) sit in one aligned uint -> gathers use full
// 64B sectors (16 lanes x 4B).
// ---------------------------------------------------------------------------

// ---------------------------------------------------------------------------
// Build bucketed CSR by dst, packing (eid, src). deg pre-zeroed.
// Pad slots keep garbage; readers clamp indices and mask contributions.
// ---------------------------------------------------------------------------
__global__ __launch_bounds__(256) void fill_csr(
    const int* __restrict__ dst, const int* __restrict__ src,
    int* __restrict__ deg, int2* __restrict__ ecsr)
{
    int e = blockIdx.x * blockDim.x + threadIdx.x;
    if (e < N_EDGES) {
        int d = dst[e];
        int slot = atomicAdd(&deg[d], 1);
        if (slot < CAP) ecsr[d * CAP + slot] = make_int2(e, src[e]);
    }
}

// fp32 [N][D] -> permuted bf16. One thread per output uint (pair).
template <int DIN>
__global__ __launch_bounds__(256) void cvt_perm_kernel(
    const float* __restrict__ in, unsigned int* __restrict__ out, int total)
{
    int t = blockIdx.x * blockDim.x + threadIdx.x;   // t < N*DIN/2
    if (t < total) {
        const int m2 = t % (DIN / 2);    // uint index within row
        const int n  = t / (DIN / 2);
        const int p  = m2 >> 4;
        const int c  = m2 & 15;
        const float lo = in[(size_t)n * DIN + 32 * p + c];
        const float hi = in[(size_t)n * DIN + 32 * p + 16 + c];
        out[t] = (unsigned int)(unsigned short)f2bf(lo) |
                 ((unsigned int)(unsigned short)f2bf(hi) << 16);
    }
}

// ---------------------------------------------------------------------------
// Persistent-wave MFMA gather, permuted bf16 in/out:
//   hpre[n] = perm_bf16( hin[n] + sum_e relu(hin[src[e]] + ea[e]@We + be) )
// B fragments (We rows + bias row at k=16, A[k=16]=1) built once per wave.
// Per 16-edge chunk: packed int2 CSR (lanes 0-15), A from fp32 ea rows
// (64B-aligned), NB MFMAs; x-gather as ONE uint per (row, pair) = full
// 64B sectors. Plain stores, no atomics.
// ---------------------------------------------------------------------------
template <int DIN>
__global__ __launch_bounds__(256, 8) void gather_v5(
    const unsigned short* __restrict__ hin,  // [N,DIN] bf16 permuted
    const float* __restrict__ ea,            // [E,16] fp32
    const int* __restrict__ deg,
    const int2* __restrict__ ecsr,           // [N,CAP] (eid, src)
    const float* __restrict__ We,            // [16,DIN] fp32
    const float* __restrict__ be,            // [DIN]
    unsigned short* __restrict__ hpre)       // [N,DIN] bf16 permuted out
{
    constexpr int NB = DIN / 16;
    constexpr int NP = DIN / 32;

    const int lane = threadIdx.x & 63;
    const int col = lane & 15;   // A row (edge slot) AND output dim-in-block
    const int grp = lane >> 4;   // 0..3
    const int gwave = (blockIdx.x * blockDim.x + threadIdx.x) >> 6;
    const int nwaves = (gridDim.x * blockDim.x) >> 6;

    // --- B fragments, built once: We rows k=grp*8+j (grp<2); bias at k=16 ---
    short8v Bf[NB];
#pragma unroll
    for (int b = 0; b < NB; ++b) {
        short8v f = {};
        if (grp < 2) {
#pragma unroll
            for (int j = 0; j < 8; ++j)
                f[j] = f2bf(We[(grp * 8 + j) * DIN + b * 16 + col]);
        } else if (grp == 2) {
            f[0] = f2bf(be[b * 16 + col]);   // k=16 row = bias
        }
        Bf[b] = f;
    }

    for (int n = gwave; n < N_NODES; n += nwaves) {
        const int dgc = min(deg[n], CAP);
        const int nch = (dgc + 15) >> 4;

        float accv[NB];
#pragma unroll
        for (int b = 0; b < NB; ++b) accv[b] = 0.0f;

        for (int c = 0; c < nch; ++c) {
            const int base = n * CAP + c * 16;
            const int vc = dgc - c * 16;   // valid edges in this chunk (1..16)

            // lanes 0-15: one 8B load covers eid AND src (clamped vs garbage)
            int e_l = 0, s_l = 0;
            if (lane < 16) {
                const int2 pr = ecsr[base + lane];
                e_l = min(max(pr.x, 0), N_EDGES - 1);
                s_l = min(max(pr.y, 0), N_NODES - 1);
            }

            // A fragment: row=col -> edge id held by lane col (fp32 ea, 64B row)
            const int e_col = __shfl(e_l, col);
            short8v Af = {};
            if (grp < 2) {
                const float* ap = ea + (size_t)e_col * 16 + grp * 8;
                const float4 a0 = *(const float4*)(ap);
                const float4 a1 = *(const float4*)(ap + 4);
                Af[0] = f2bf(a0.x); Af[1] = f2bf(a0.y);
                Af[2] = f2bf(a0.z); Af[3] = f2bf(a0.w);
                Af[4] = f2bf(a1.x); Af[5] = f2bf(a1.y);
                Af[6] = f2bf(a1.z); Af[7] = f2bf(a1.w);
            } else if (grp == 2) {
                Af[0] = (short)0x3F80;   // bf16 1.0 -> picks up bias row
            }

            // src ids for this lane's 4 output rows (edges 4*grp+r)
            int sid[4];
            float msk[4];
#pragma unroll
            for (int r = 0; r < 4; ++r) {
                sid[r] = __shfl(s_l, 4 * grp + r);
                msk[r] = (4 * grp + r) < vc ? 1.0f : 0.0f;
            }

            // process dim-blocks in pairs: one uint x-load serves both blocks
#pragma unroll
            for (int p = 0; p < NP; ++p) {
                const f32x4 zero = {0.0f, 0.0f, 0.0f, 0.0f};
                f32x4 lin0 = __builtin_amdgcn_mfma_f32_16x16x32_bf16(Af, Bf[2 * p], zero, 0, 0, 0);
                f32x4 lin1 = __builtin_amdgcn_mfma_f32_16x16x32_bf16(Af, Bf[2 * p + 1], zero, 0, 0, 0);
                float part0 = 0.0f, part1 = 0.0f;
#pragma unroll
                for (int r = 0; r < 4; ++r) {
                    const unsigned int u = *(const unsigned int*)
                        (hin + (size_t)sid[r] * DIN + 32 * p + 2 * col);
                    const float xlo = bf2f((unsigned short)(u & 0xffffu));
                    const float xhi = bf2f((unsigned short)(u >> 16));
                    part0 = fmaf(msk[r], fmaxf(xlo + lin0[r], 0.0f), part0);
                    part1 = fmaf(msk[r], fmaxf(xhi + lin1[r], 0.0f), part1);
                }
                part0 += __shfl_xor(part0, 16);
                part0 += __shfl_xor(part0, 32);
                part1 += __shfl_xor(part1, 16);
                part1 += __shfl_xor(part1, 32);
                accv[2 * p] += part0;
                accv[2 * p + 1] += part1;
            }
        }

        // self term + store (fused h = x + agg), permuted bf16 out
        if (lane < 16) {
#pragma unroll
            for (int p = 0; p < NP; ++p) {
                const unsigned int u = *(const unsigned int*)
                    (hin + (size_t)n * DIN + 32 * p + 2 * lane);
                const float lo = bf2f((unsigned short)(u & 0xffffu)) + accv[2 * p];
                const float hi = bf2f((unsigned short)(u >> 16)) + accv[2 * p + 1];
                *(unsigned int*)(hpre + (size_t)n * DIN + 32 * p + 2 * lane) =
                    (unsigned int)(unsigned short)f2bf(lo) |
                    ((unsigned int)(unsigned short)f2bf(hi) << 16);
            }
        }
    }
}

// ---------------------------------------------------------------------------
// Tiled GIN MLP, permuted bf16 input: v = relu( relu(h@Wa+ba) @ Wb + bb )
// 32 nodes/block, 256 threads. MODE 0: write v permuted bf16 (h1).
// MODE 1: run-length pool into pooled.
// ---------------------------------------------------------------------------
template <int DIN, int MODE>
__global__ __launch_bounds__(256) void mlp_kernel(
    const unsigned short* __restrict__ hpre,  // [N, DIN] bf16 permuted
    const float* __restrict__ Wa,     // [DIN,128]
    const float* __restrict__ ba,
    const float* __restrict__ Wb,     // [128,128]
    const float* __restrict__ bb,
    unsigned short* __restrict__ h1out,  // MODE 0 (permuted)
    const int* __restrict__ batch,       // MODE 1
    float* __restrict__ pooled)          // MODE 1 (pre-zeroed)
{
    constexpr int TN = 32;
    constexpr int PAD = 4;
    __shared__ float sh[TN][DIN + PAD];
    __shared__ float su[TN][128 + PAD];

    const int n0 = blockIdx.x * TN;
    const int tid = threadIdx.x;

    // stage + un-permute: ushort4 at row-pos colc = 32p+4q ->
    //   dims {32p+2q, 32p+16+2q, 32p+2q+1, 32p+16+2q+1}
    constexpr int TOT = TN * DIN;
    for (int f = tid * 4; f < TOT; f += 256 * 4) {
        const int row = f / DIN, colc = f % DIN;
        const int n = n0 + row;
        ushort4 u = make_ushort4(0, 0, 0, 0);
        if (n < N_NODES) u = *(const ushort4*)(hpre + (size_t)n * DIN + colc);
        const int p = colc >> 5;
        const int q = (colc & 31) >> 2;
        const int d0 = 32 * p + 2 * q;
        const int d1 = 32 * p + 16 + 2 * q;
        sh[row][d0]     = bf2f(u.x);
        sh[row][d1]     = bf2f(u.y);
        sh[row][d0 + 1] = bf2f(u.z);
        sh[row][d1 + 1] = bf2f(u.w);
    }
    __syncthreads();

    const int g = tid & 31;
    const int qb = (tid >> 5) * 4;

    float acc[4][4];
#pragma unroll
    for (int q = 0; q < 4; ++q)
#pragma unroll
        for (int j = 0; j < 4; ++j) acc[q][j] = 0.0f;

    for (int k = 0; k < DIN; ++k) {
        const float4 w = *(const float4*)(Wa + (size_t)k * 128 + g * 4);
        const float h0 = sh[qb + 0][k], h1v = sh[qb + 1][k],
                    h2 = sh[qb + 2][k], h3 = sh[qb + 3][k];
        acc[0][0] = fmaf(h0, w.x, acc[0][0]); acc[0][1] = fmaf(h0, w.y, acc[0][1]);
        acc[0][2] = fmaf(h0, w.z, acc[0][2]); acc[0][3] = fmaf(h0, w.w, acc[0][3]);
        acc[1][0] = fmaf(h1v, w.x, acc[1][0]); acc[1][1] = fmaf(h1v, w.y, acc[1][1]);
        acc[1][2] = fmaf(h1v, w.z, acc[1][2]); acc[1][3] = fmaf(h1v, w.w, acc[1][3]);
        acc[2][0] = fmaf(h2, w.x, acc[2][0]); acc[2][1] = fmaf(h2, w.y, acc[2][1]);
        acc[2][2] = fmaf(h2, w.z, acc[2][2]); acc[2][3] = fmaf(h2, w.w, acc[2][3]);
        acc[3][0] = fmaf(h3, w.x, acc[3][0]); acc[3][1] = fmaf(h3, w.y, acc[3][1]);
        acc[3][2] = fmaf(h3, w.z, acc[3][2]); acc[3][3] = fmaf(h3, w.w, acc[3][3]);
    }

    const float4 bav = *(const float4*)(ba + g * 4);
#pragma unroll
    for (int q = 0; q < 4; ++q) {
        float4 u;
        u.x = fmaxf(acc[q][0] + bav.x, 0.f);
        u.y = fmaxf(acc[q][1] + bav.y, 0.f);
        u.z = fmaxf(acc[q][2] + bav.z, 0.f);
        u.w = fmaxf(acc[q][3] + bav.w, 0.f);
        *(float4*)&su[qb + q][g * 4] = u;
    }
    __syncthreads();

#pragma unroll
    for (int q = 0; q < 4; ++q)
#pragma unroll
        for (int j = 0; j < 4; ++j) acc[q][j] = 0.0f;

    for (int k = 0; k < 128; ++k) {
        const float4 w = *(const float4*)(Wb + (size_t)k * 128 + g * 4);
        const float u0 = su[qb + 0][k], u1 = su[qb + 1][k],
                    u2 = su[qb + 2][k], u3 = su[qb + 3][k];
        acc[0][0] = fmaf(u0, w.x, acc[0][0]); acc[0][1] = fmaf(u0, w.y, acc[0][1]);
        acc[0][2] = fmaf(u0, w.z, acc[0][2]); acc[0][3] = fmaf(u0, w.w, acc[0][3]);
        acc[1][0] = fmaf(u1, w.x, acc[1][0]); acc[1][1] = fmaf(u1, w.y, acc[1][1]);
        acc[1][2] = fmaf(u1, w.z, acc[1][2]); acc[1][3] = fmaf(u1, w.w, acc[1][3]);
        acc[2][0] = fmaf(u2, w.x, acc[2][0]); acc[2][1] = fmaf(u2, w.y, acc[2][1]);
        acc[2][2] = fmaf(u2, w.z, acc[2][2]); acc[2][3] = fmaf(u2, w.w, acc[2][3]);
        acc[3][0] = fmaf(u3, w.x, acc[3][0]); acc[3][1] = fmaf(u3, w.y, acc[3][1]);
        acc[3][2] = fmaf(u3, w.z, acc[3][2]); acc[3][3] = fmaf(u3, w.w, acc[3][3]);
    }

    const float4 bbv = *(const float4*)(bb + g * 4);

    if (MODE == 0) {
        // write permuted: dim d=4g+j -> m = 32p + 2*(cbase+j) + half
        const int p = g >> 3;
        const int half = (g >> 2) & 1;
        const int cbase = (4 * g) & 15;
#pragma unroll
        for (int q = 0; q < 4; ++q) {
            const int n = n0 + qb + q;
            if (n < N_NODES) {
                unsigned short* rowp = h1out + (size_t)n * 128 + 32 * p + half;
                rowp[2 * (cbase + 0)] = (unsigned short)f2bf(fmaxf(acc[q][0] + bbv.x, 0.f));
                rowp[2 * (cbase + 1)] = (unsigned short)f2bf(fmaxf(acc[q][1] + bbv.y, 0.f));
                rowp[2 * (cbase + 2)] = (unsigned short)f2bf(fmaxf(acc[q][2] + bbv.z, 0.f));
                rowp[2 * (cbase + 3)] = (unsigned short)f2bf(fmaxf(acc[q][3] + bbv.w, 0.f));
            }
        }
    } else {
#pragma unroll
        for (int q = 0; q < 4; ++q) {
            float4 v;
            v.x = fmaxf(acc[q][0] + bbv.x, 0.f);
            v.y = fmaxf(acc[q][1] + bbv.y, 0.f);
            v.z = fmaxf(acc[q][2] + bbv.z, 0.f);
            v.w = fmaxf(acc[q][3] + bbv.w, 0.f);
            *(float4*)&sh[qb + q][g * 4] = v;
        }
        __syncthreads();
        if (tid < 128) {
            const int d = tid;
            const int lim = min(TN, N_NODES - n0);
            float s = 0.0f;
            int bprev = -1;
            for (int q = 0; q < lim; ++q) {
                const int b = batch[n0 + q];
                if (b != bprev) {
                    if (bprev >= 0) atomicAdd(&pooled[bprev * 128 + d], s);
                    s = 0.0f;
                    bprev = b;
                }
                s += sh[q][d];
            }
            if (bprev >= 0) atomicAdd(&pooled[bprev * 128 + d], s);
        }
    }
}

// ---------------------------------------------------------------------------
// Final FC
// ---------------------------------------------------------------------------
__global__ __launch_bounds__(128) void fc_kernel(
    const float* __restrict__ pooled,
    const float* __restrict__ Wfc,
    const float* __restrict__ bfc,
    float* __restrict__ out)
{
    const int g = blockIdx.x;
    const int d = threadIdx.x;
    __shared__ float sp[128];
    sp[d] = pooled[g * 128 + d];
    __syncthreads();
    float acc = bfc[d];
    for (int k = 0; k < 128; ++k) acc = fmaf(sp[k], Wfc[k * 128 + d], acc);
    out[g * 128 + d] = acc;
}

extern "C" void kernel_launch(void* const* d_in, const int* in_sizes, int n_in,
                              void* d_out, int out_size, void* d_ws, size_t ws_size,
                              hipStream_t stream) {
    const float* x    = (const float*)d_in[0];
    const int*   eidx = (const int*)d_in[1];
    const float* ea   = (const float*)d_in[2];
    const int*   batch= (const int*)d_in[3];
    const float* We1  = (const float*)d_in[4];
    const float* be1  = (const float*)d_in[5];
    const float* W1a  = (const float*)d_in[6];
    const float* b1a  = (const float*)d_in[7];
    const float* W1b  = (const float*)d_in[8];
    const float* b1b  = (const float*)d_in[9];
    const float* We2  = (const float*)d_in[10];
    const float* be2  = (const float*)d_in[11];
    const float* W2a  = (const float*)d_in[12];
    const float* b2a  = (const float*)d_in[13];
    const float* W2b  = (const float*)d_in[14];
    const float* b2b  = (const float*)d_in[15];
    const float* Wfc  = (const float*)d_in[16];
    const float* bfc  = (const float*)d_in[17];
    float* out = (float*)d_out;

    const int* srcp = eidx;
    const int* dstp = eidx + N_EDGES;

    // workspace: 45.3 MB (x16 aliases h1 buffer)
    char* w = (char*)d_ws;
    unsigned short* hpre = (unsigned short*)w;  w += (size_t)N_NODES * 128 * 2;
    unsigned short* h1 = (unsigned short*)w;    w += (size_t)N_NODES * 128 * 2;
    int* deg  = (int*)w;                        w += (size_t)N_NODES * 4;
    int2* ecsr = (int2*)w;                      w += (size_t)N_NODES * CAP * 8;
    float* pooled = (float*)w;

    // x16 (9.6 MB, permuted) aliases h1's buffer: dead once mlp1 writes h1.
    unsigned short* x16 = h1;

    // ---- prep: CSR (packed eid+src) and permuted bf16 x ----
    hipMemsetAsync(deg, 0, (size_t)N_NODES * 4, stream);
    fill_csr<<<(N_EDGES + 255) / 256, 256, 0, stream>>>(dstp, srcp, deg, ecsr);
    {
        const int total = N_NODES * 96 / 2;
        cvt_perm_kernel<96><<<(total + 255) / 256, 256, 0, stream>>>(
            x, (unsigned int*)x16, total);
    }

    const int gblocks = 2048;   // 8192 persistent waves (8/SIMD)

    // ---- layer 1 ----
    gather_v5<96><<<gblocks, 256, 0, stream>>>(
        x16, ea, deg, ecsr, We1, be1, hpre);
    mlp_kernel<96, 0><<<(N_NODES + 31) / 32, 256, 0, stream>>>(
        hpre, W1a, b1a, W1b, b1b, h1, nullptr, nullptr);

    // ---- layer 2 ----
    gather_v5<128><<<gblocks, 256, 0, stream>>>(
        h1, ea, deg, ecsr, We2, be2, hpre);
    hipMemsetAsync(pooled, 0, (size_t)N_GRAPHS * 128 * 4, stream);
    mlp_kernel<128, 1><<<(N_NODES + 31) / 32, 256, 0, stream>>>(
        hpre, W2a, b2a, W2b, b2b, nullptr, batch, pooled);

    // ---- readout ----
    fc_kernel<<<N_GRAPHS, 128, 0, stream>>>(pooled, Wfc, bfc, out);
}

// Round 9
// 377.247 us; speedup vs baseline: 1.2673x; 1.2247x over previous
//
#include <hip/hip_runtime.h>
#include <hip/hip_bf16.h>

#define N_NODES 50000
#define N_EDGES 800000
#define N_GRAPHS 512
#define CAP 48   // 3 tiles of 16; P(deg>48) ~ 5e-11 for Poisson(16)

typedef __attribute__((ext_vector_type(8))) short short8v;   // 8 bf16
typedef __attribute__((ext_vector_type(4))) float f32x4;

__device__ inline float bf2f(unsigned short u) {
    union { unsigned int i; float f; } v; v.i = ((unsigned int)u) << 16; return v.f;
}
__device__ inline short f2bf(float f) {
    __hip_bfloat16 h = __float2bfloat16(f);
    return *reinterpret_cast<short*>(&h);
}

// ---------------------------------------------------------------------------
// PERMUTED bf16 row layout (row of D dims, D%32==0):
//   memory position m = 32*p + 2*c + half  <->  dim d = 32*p + 16*half + c
// pairs (32p+c, 32p+16+c) share one aligned uint -> full 64B sectors.
// ---------------------------------------------------------------------------

__global__ __launch_bounds__(256) void fill_csr(
    const int* __restrict__ dst, const int* __restrict__ src,
    int* __restrict__ deg, int2* __restrict__ ecsr)
{
    int e = blockIdx.x * blockDim.x + threadIdx.x;
    if (e < N_EDGES) {
        int d = dst[e];
        int slot = atomicAdd(&deg[d], 1);
        if (slot < CAP) ecsr[d * CAP + slot] = make_int2(e, src[e]);
    }
}

// fp32 [N][D] -> permuted bf16. One thread per output uint (pair).
template <int DIN>
__global__ __launch_bounds__(256) void cvt_perm_kernel(
    const float* __restrict__ in, unsigned int* __restrict__ out, int total)
{
    int t = blockIdx.x * blockDim.x + threadIdx.x;   // t < N*DIN/2
    if (t < total) {
        const int m2 = t % (DIN / 2);
        const int n  = t / (DIN / 2);
        const int p  = m2 >> 4;
        const int c  = m2 & 15;
        const float lo = in[(size_t)n * DIN + 32 * p + c];
        const float hi = in[(size_t)n * DIN + 32 * p + 16 + c];
        out[t] = (unsigned int)(unsigned short)f2bf(lo) |
                 ((unsigned int)(unsigned short)f2bf(hi) << 16);
    }
}

// W[k][128] fp32 -> WT[d][K] bf16 (transpose + convert). K = input dim.
template <int K>
__global__ __launch_bounds__(256) void cvtT_kernel(
    const float* __restrict__ W, unsigned short* __restrict__ WT)
{
    int t = blockIdx.x * blockDim.x + threadIdx.x;
    if (t < 128 * K) {
        const int d = t / K;
        const int k = t % K;
        WT[t] = (unsigned short)f2bf(W[k * 128 + d]);
    }
}

// ---------------------------------------------------------------------------
// Persistent-wave MFMA gather, permuted bf16 in/out, EXEC-MASKED loads:
//   hpre[n] = perm_bf16( hin[n] + sum_e relu(hin[src[e]] + ea[e]@We + be) )
// B fragments (We rows + bias row at k=16, A[k=16]=1) built once per wave.
// Padding slots (slot >= vc) fetch NOTHING (masked loads), eliminating
// ~30% garbage fetch vs v5. Plain stores, no atomics.
// ---------------------------------------------------------------------------
template <int DIN>
__global__ __launch_bounds__(256, 8) void gather_v6(
    const unsigned short* __restrict__ hin,  // [N,DIN] bf16 permuted
    const float* __restrict__ ea,            // [E,16] fp32
    const int* __restrict__ deg,
    const int2* __restrict__ ecsr,           // [N,CAP] (eid, src)
    const float* __restrict__ We,            // [16,DIN] fp32
    const float* __restrict__ be,            // [DIN]
    unsigned short* __restrict__ hpre)       // [N,DIN] bf16 permuted out
{
    constexpr int NB = DIN / 16;
    constexpr int NP = DIN / 32;

    const int lane = threadIdx.x & 63;
    const int col = lane & 15;
    const int grp = lane >> 4;
    const int gwave = (blockIdx.x * blockDim.x + threadIdx.x) >> 6;
    const int nwaves = (gridDim.x * blockDim.x) >> 6;

    // B fragments: We rows k=grp*8+j (grp<2); bias row at k=16 (grp2, j=0)
    short8v Bf[NB];
#pragma unroll
    for (int b = 0; b < NB; ++b) {
        short8v f = {};
        if (grp < 2) {
#pragma unroll
            for (int j = 0; j < 8; ++j)
                f[j] = f2bf(We[(grp * 8 + j) * DIN + b * 16 + col]);
        } else if (grp == 2) {
            f[0] = f2bf(be[b * 16 + col]);
        }
        Bf[b] = f;
    }

    for (int n = gwave; n < N_NODES; n += nwaves) {
        const int dgc = min(deg[n], CAP);
        const int nch = (dgc + 15) >> 4;

        float accv[NB];
#pragma unroll
        for (int b = 0; b < NB; ++b) accv[b] = 0.0f;

        for (int c = 0; c < nch; ++c) {
            const int base = n * CAP + c * 16;
            const int vc = dgc - c * 16;   // valid edges in this chunk (1..16)

            // lanes 0..vc-1: one 8B load covers eid AND src
            int e_l = 0, s_l = 0;
            if (lane < vc) {
                const int2 pr = ecsr[base + lane];
                e_l = pr.x;
                s_l = pr.y;
            }

            // A fragment: row=col -> edge id held by lane col. Masked: only
            // valid rows load (invalid rows stay zero; their lin is masked).
            const int e_col = __shfl(e_l, col);
            short8v Af = {};
            if (grp < 2) {
                if (col < vc) {
                    const float* ap = ea + (size_t)e_col * 16 + grp * 8;
                    const float4 a0 = *(const float4*)(ap);
                    const float4 a1 = *(const float4*)(ap + 4);
                    Af[0] = f2bf(a0.x); Af[1] = f2bf(a0.y);
                    Af[2] = f2bf(a0.z); Af[3] = f2bf(a0.w);
                    Af[4] = f2bf(a1.x); Af[5] = f2bf(a1.y);
                    Af[6] = f2bf(a1.z); Af[7] = f2bf(a1.w);
                }
            } else if (grp == 2) {
                Af[0] = (short)0x3F80;   // bf16 1.0 -> bias row
            }

            // src ids for this lane's 4 output rows (edges 4*grp+r)
            int sid[4];
#pragma unroll
            for (int r = 0; r < 4; ++r) sid[r] = __shfl(s_l, 4 * grp + r);

            // dim-block pairs: one uint x-load serves both blocks; loads
            // exec-masked per r -> padding slots fetch nothing.
#pragma unroll
            for (int p = 0; p < NP; ++p) {
                const f32x4 zero = {0.0f, 0.0f, 0.0f, 0.0f};
                f32x4 lin0 = __builtin_amdgcn_mfma_f32_16x16x32_bf16(Af, Bf[2 * p], zero, 0, 0, 0);
                f32x4 lin1 = __builtin_amdgcn_mfma_f32_16x16x32_bf16(Af, Bf[2 * p + 1], zero, 0, 0, 0);
                float part0 = 0.0f, part1 = 0.0f;
#pragma unroll
                for (int r = 0; r < 4; ++r) {
                    if (4 * grp + r < vc) {
                        const unsigned int u = *(const unsigned int*)
                            (hin + (size_t)sid[r] * DIN + 32 * p + 2 * col);
                        const float xlo = bf2f((unsigned short)(u & 0xffffu));
                        const float xhi = bf2f((unsigned short)(u >> 16));
                        part0 += fmaxf(xlo + lin0[r], 0.0f);
                        part1 += fmaxf(xhi + lin1[r], 0.0f);
                    }
                }
                part0 += __shfl_xor(part0, 16);
                part0 += __shfl_xor(part0, 32);
                part1 += __shfl_xor(part1, 16);
                part1 += __shfl_xor(part1, 32);
                accv[2 * p] += part0;
                accv[2 * p + 1] += part1;
            }
        }

        // self term + store (fused h = x + agg), permuted bf16 out
        if (lane < 16) {
#pragma unroll
            for (int p = 0; p < NP; ++p) {
                const unsigned int u = *(const unsigned int*)
                    (hin + (size_t)n * DIN + 32 * p + 2 * lane);
                const float lo = bf2f((unsigned short)(u & 0xffffu)) + accv[2 * p];
                const float hi = bf2f((unsigned short)(u >> 16)) + accv[2 * p + 1];
                *(unsigned int*)(hpre + (size_t)n * DIN + 32 * p + 2 * lane) =
                    (unsigned int)(unsigned short)f2bf(lo) |
                    ((unsigned int)(unsigned short)f2bf(hi) << 16);
            }
        }
    }
}

// ---------------------------------------------------------------------------
// MFMA GIN MLP: v = relu( relu(h@Wa+ba) @ Wb + bb ), h from permuted bf16.
// 32 nodes/block, 256 threads = 4 waves; wave w owns dim-tiles {2w, 2w+1}
// and both node-tiles. Fragment layout identical to gather (proven):
//   A: row=lane&15, k=grp*8+j;  B[k][col];  D: col=lane&15, row=grp*4+reg.
// Weights pre-transposed bf16: WT[d][K]. MODE 0: permuted bf16 h1 out
// (uint pair per lane = full lines). MODE 1: run-length pool.
// ---------------------------------------------------------------------------
template <int DIN, int MODE>
__global__ __launch_bounds__(256) void mlp_mfma(
    const unsigned short* __restrict__ hpre,  // [N,DIN] bf16 permuted
    const unsigned short* __restrict__ WaT,   // [128][DIN] bf16
    const float* __restrict__ ba,
    const unsigned short* __restrict__ WbT,   // [128][128] bf16
    const float* __restrict__ bb,
    unsigned short* __restrict__ h1out,       // MODE 0 (permuted)
    const int* __restrict__ batch,            // MODE 1
    float* __restrict__ pooled)               // MODE 1 (pre-zeroed)
{
    constexpr int KS1 = DIN / 32;
    __shared__ unsigned short hls[32][DIN + 8];
    __shared__ unsigned short uls[32][128 + 8];
    __shared__ float vls[(MODE == 1) ? 32 : 1][(MODE == 1) ? 132 : 1];

    const int n0 = blockIdx.x * 32;
    const int tid = threadIdx.x;

    // stage + un-permute hpre tile into LDS (bf16)
    for (int f = tid * 4; f < 32 * DIN; f += 1024) {
        const int row = f / DIN, colc = f % DIN;
        const int n = n0 + row;
        ushort4 u = make_ushort4(0, 0, 0, 0);
        if (n < N_NODES) u = *(const ushort4*)(hpre + (size_t)n * DIN + colc);
        const int p = colc >> 5;
        const int q = (colc & 31) >> 2;
        hls[row][32 * p + 2 * q]          = u.x;
        hls[row][32 * p + 16 + 2 * q]     = u.y;
        hls[row][32 * p + 2 * q + 1]      = u.z;
        hls[row][32 * p + 16 + 2 * q + 1] = u.w;
    }
    __syncthreads();

    const int lane = tid & 63;
    const int w = tid >> 6;       // wave 0..3 -> dim-tiles 2w, 2w+1
    const int col = lane & 15;
    const int grp = lane >> 4;

    // ---- GEMM1: u = relu(h @ Wa + ba) ----
    f32x4 acc00 = {0,0,0,0}, acc01 = {0,0,0,0}, acc10 = {0,0,0,0}, acc11 = {0,0,0,0};
#pragma unroll
    for (int ks = 0; ks < KS1; ++ks) {
        const short8v A0 = *(const short8v*)&hls[col][ks * 32 + grp * 8];
        const short8v A1 = *(const short8v*)&hls[16 + col][ks * 32 + grp * 8];
        const short8v B0 = *(const short8v*)&WaT[(size_t)(2 * w * 16 + col) * DIN + ks * 32 + grp * 8];
        const short8v B1 = *(const short8v*)&WaT[(size_t)((2 * w + 1) * 16 + col) * DIN + ks * 32 + grp * 8];
        acc00 = __builtin_amdgcn_mfma_f32_16x16x32_bf16(A0, B0, acc00, 0, 0, 0);
        acc01 = __builtin_amdgcn_mfma_f32_16x16x32_bf16(A0, B1, acc01, 0, 0, 0);
        acc10 = __builtin_amdgcn_mfma_f32_16x16x32_bf16(A1, B0, acc10, 0, 0, 0);
        acc11 = __builtin_amdgcn_mfma_f32_16x16x32_bf16(A1, B1, acc11, 0, 0, 0);
    }
    const float ba0 = ba[2 * w * 16 + col];
    const float ba1 = ba[(2 * w + 1) * 16 + col];
#pragma unroll
    for (int i = 0; i < 4; ++i) {
        const int r0 = grp * 4 + i;
        uls[r0][2 * w * 16 + col]            = (unsigned short)f2bf(fmaxf(acc00[i] + ba0, 0.f));
        uls[r0][(2 * w + 1) * 16 + col]      = (unsigned short)f2bf(fmaxf(acc01[i] + ba1, 0.f));
        uls[16 + r0][2 * w * 16 + col]       = (unsigned short)f2bf(fmaxf(acc10[i] + ba0, 0.f));
        uls[16 + r0][(2 * w + 1) * 16 + col] = (unsigned short)f2bf(fmaxf(acc11[i] + ba1, 0.f));
    }
    __syncthreads();

    // ---- GEMM2: v = relu(u @ Wb + bb) ----
    acc00 = (f32x4){0,0,0,0}; acc01 = (f32x4){0,0,0,0};
    acc10 = (f32x4){0,0,0,0}; acc11 = (f32x4){0,0,0,0};
#pragma unroll
    for (int ks = 0; ks < 4; ++ks) {
        const short8v A0 = *(const short8v*)&uls[col][ks * 32 + grp * 8];
        const short8v A1 = *(const short8v*)&uls[16 + col][ks * 32 + grp * 8];
        const short8v B0 = *(const short8v*)&WbT[(size_t)(2 * w * 16 + col) * 128 + ks * 32 + grp * 8];
        const short8v B1 = *(const short8v*)&WbT[(size_t)((2 * w + 1) * 16 + col) * 128 + ks * 32 + grp * 8];
        acc00 = __builtin_amdgcn_mfma_f32_16x16x32_bf16(A0, B0, acc00, 0, 0, 0);
        acc01 = __builtin_amdgcn_mfma_f32_16x16x32_bf16(A0, B1, acc01, 0, 0, 0);
        acc10 = __builtin_amdgcn_mfma_f32_16x16x32_bf16(A1, B0, acc10, 0, 0, 0);
        acc11 = __builtin_amdgcn_mfma_f32_16x16x32_bf16(A1, B1, acc11, 0, 0, 0);
    }
    const float bb0 = bb[2 * w * 16 + col];
    const float bb1 = bb[(2 * w + 1) * 16 + col];

    if (MODE == 0) {
        // dims d0=32w+col (p=w,half=0), d1=32w+16+col (p=w,half=1): the lane's
        // dt-pair IS the permute pair -> one uint store, full 64B lines.
#pragma unroll
        for (int i = 0; i < 4; ++i) {
            const int nA = n0 + grp * 4 + i;
            if (nA < N_NODES) {
                const float v0 = fmaxf(acc00[i] + bb0, 0.f);
                const float v1 = fmaxf(acc01[i] + bb1, 0.f);
                *(unsigned int*)(h1out + (size_t)nA * 128 + 32 * w + 2 * col) =
                    (unsigned int)(unsigned short)f2bf(v0) |
                    ((unsigned int)(unsigned short)f2bf(v1) << 16);
            }
            const int nB = n0 + 16 + grp * 4 + i;
            if (nB < N_NODES) {
                const float v0 = fmaxf(acc10[i] + bb0, 0.f);
                const float v1 = fmaxf(acc11[i] + bb1, 0.f);
                *(unsigned int*)(h1out + (size_t)nB * 128 + 32 * w + 2 * col) =
                    (unsigned int)(unsigned short)f2bf(v0) |
                    ((unsigned int)(unsigned short)f2bf(v1) << 16);
            }
        }
    } else {
#pragma unroll
        for (int i = 0; i < 4; ++i) {
            const int r0 = grp * 4 + i;
            vls[r0][2 * w * 16 + col]            = fmaxf(acc00[i] + bb0, 0.f);
            vls[r0][(2 * w + 1) * 16 + col]      = fmaxf(acc01[i] + bb1, 0.f);
            vls[16 + r0][2 * w * 16 + col]       = fmaxf(acc10[i] + bb0, 0.f);
            vls[16 + r0][(2 * w + 1) * 16 + col] = fmaxf(acc11[i] + bb1, 0.f);
        }
        __syncthreads();
        if (tid < 128) {
            const int d = tid;
            const int lim = min(32, N_NODES - n0);
            float s = 0.0f;
            int bprev = -1;
            for (int q = 0; q < lim; ++q) {
                const int b = batch[n0 + q];
                if (b != bprev) {
                    if (bprev >= 0) atomicAdd(&pooled[bprev * 128 + d], s);
                    s = 0.0f;
                    bprev = b;
                }
                s += vls[q][d];
            }
            if (bprev >= 0) atomicAdd(&pooled[bprev * 128 + d], s);
        }
    }
}

// ---------------------------------------------------------------------------
// Final FC
// ---------------------------------------------------------------------------
__global__ __launch_bounds__(128) void fc_kernel(
    const float* __restrict__ pooled,
    const float* __restrict__ Wfc,
    const float* __restrict__ bfc,
    float* __restrict__ out)
{
    const int g = blockIdx.x;
    const int d = threadIdx.x;
    __shared__ float sp[128];
    sp[d] = pooled[g * 128 + d];
    __syncthreads();
    float acc = bfc[d];
    for (int k = 0; k < 128; ++k) acc = fmaf(sp[k], Wfc[k * 128 + d], acc);
    out[g * 128 + d] = acc;
}

extern "C" void kernel_launch(void* const* d_in, const int* in_sizes, int n_in,
                              void* d_out, int out_size, void* d_ws, size_t ws_size,
                              hipStream_t stream) {
    const float* x    = (const float*)d_in[0];
    const int*   eidx = (const int*)d_in[1];
    const float* ea   = (const float*)d_in[2];
    const int*   batch= (const int*)d_in[3];
    const float* We1  = (const float*)d_in[4];
    const float* be1  = (const float*)d_in[5];
    const float* W1a  = (const float*)d_in[6];
    const float* b1a  = (const float*)d_in[7];
    const float* W1b  = (const float*)d_in[8];
    const float* b1b  = (const float*)d_in[9];
    const float* We2  = (const float*)d_in[10];
    const float* be2  = (const float*)d_in[11];
    const float* W2a  = (const float*)d_in[12];
    const float* b2a  = (const float*)d_in[13];
    const float* W2b  = (const float*)d_in[14];
    const float* b2b  = (const float*)d_in[15];
    const float* Wfc  = (const float*)d_in[16];
    const float* bfc  = (const float*)d_in[17];
    float* out = (float*)d_out;

    const int* srcp = eidx;
    const int* dstp = eidx + N_EDGES;

    // workspace: ~45.5 MB
    char* w = (char*)d_ws;
    unsigned short* hpre = (unsigned short*)w;  w += (size_t)N_NODES * 128 * 2;
    unsigned short* h1 = (unsigned short*)w;    w += (size_t)N_NODES * 128 * 2;
    int* deg  = (int*)w;                        w += (size_t)N_NODES * 4;
    int2* ecsr = (int2*)w;                      w += (size_t)N_NODES * CAP * 8;
    float* pooled = (float*)w;                  w += (size_t)N_GRAPHS * 128 * 4;
    unsigned short* W1aT = (unsigned short*)w;  w += (size_t)128 * 96 * 2;
    unsigned short* W1bT = (unsigned short*)w;  w += (size_t)128 * 128 * 2;
    unsigned short* W2aT = (unsigned short*)w;  w += (size_t)128 * 128 * 2;
    unsigned short* W2bT = (unsigned short*)w;  w += (size_t)128 * 128 * 2;

    // x16 (9.6 MB, permuted) aliases h1's buffer: dead once mlp1 writes h1.
    unsigned short* x16 = h1;

    // ---- prep: CSR, permuted bf16 x, transposed bf16 MLP weights ----
    hipMemsetAsync(deg, 0, (size_t)N_NODES * 4, stream);
    fill_csr<<<(N_EDGES + 255) / 256, 256, 0, stream>>>(dstp, srcp, deg, ecsr);
    {
        const int total = N_NODES * 96 / 2;
        cvt_perm_kernel<96><<<(total + 255) / 256, 256, 0, stream>>>(
            x, (unsigned int*)x16, total);
    }
    cvtT_kernel<96><<<(128 * 96 + 255) / 256, 256, 0, stream>>>(W1a, W1aT);
    cvtT_kernel<128><<<(128 * 128 + 255) / 256, 256, 0, stream>>>(W1b, W1bT);
    cvtT_kernel<128><<<(128 * 128 + 255) / 256, 256, 0, stream>>>(W2a, W2aT);
    cvtT_kernel<128><<<(128 * 128 + 255) / 256, 256, 0, stream>>>(W2b, W2bT);

    const int gblocks = 2048;   // 8192 persistent waves (8/SIMD)
    const int mblocks = (N_NODES + 31) / 32;

    // ---- layer 1 ----
    gather_v6<96><<<gblocks, 256, 0, stream>>>(
        x16, ea, deg, ecsr, We1, be1, hpre);
    mlp_mfma<96, 0><<<mblocks, 256, 0, stream>>>(
        hpre, W1aT, b1a, W1bT, b1b, h1, nullptr, nullptr);

    // ---- layer 2 ----
    gather_v6<128><<<gblocks, 256, 0, stream>>>(
        h1, ea, deg, ecsr, We2, be2, hpre);
    hipMemsetAsync(pooled, 0, (size_t)N_GRAPHS * 128 * 4, stream);
    mlp_mfma<128, 1><<<mblocks, 256, 0, stream>>>(
        hpre, W2aT, b2a, W2bT, b2b, nullptr, batch, pooled);

    // ---- readout ----
    fc_kernel<<<N_GRAPHS, 128, 0, stream>>>(pooled, Wfc, bfc, out);
}

// Round 10
// 369.872 us; speedup vs baseline: 1.2926x; 1.0199x over previous
//
#include <hip/hip_runtime.h>
#include <hip/hip_bf16.h>

#define N_NODES 50000
#define N_EDGES 800000
#define N_GRAPHS 512
#define CAP 48   // fallback path only

typedef __attribute__((ext_vector_type(8))) short short8v;   // 8 bf16
typedef __attribute__((ext_vector_type(4))) float f32x4;

__device__ inline float bf2f(unsigned short u) {
    union { unsigned int i; float f; } v; v.i = ((unsigned int)u) << 16; return v.f;
}
__device__ inline short f2bf(float f) {
    __hip_bfloat16 h = __float2bfloat16(f);
    return *reinterpret_cast<short*>(&h);
}

// ---------------------------------------------------------------------------
// PERMUTED bf16 row layout (row of D dims, D%32==0):
//   memory position m = 32*p + 2*c + half  <->  dim d = 32*p + 16*half + c
// ---------------------------------------------------------------------------

// ======================= compact-CSR prep (new path) =======================
__global__ __launch_bounds__(256) void count_deg(
    const int* __restrict__ dst, int* __restrict__ deg)
{
    int e = blockIdx.x * blockDim.x + threadIdx.x;
    if (e < N_EDGES) atomicAdd(&deg[dst[e]], 1);
}

__global__ __launch_bounds__(256) void assign_base(
    const int* __restrict__ deg, int* __restrict__ basep, int* __restrict__ counter)
{
    int n = blockIdx.x * blockDim.x + threadIdx.x;
    if (n < N_NODES) basep[n] = atomicAdd(counter, deg[n]);
}

// scatter edges into dst-contiguous stream: srcdst (ushort) + eadst (bf16 row)
__global__ __launch_bounds__(256) void scatter_edges(
    const int* __restrict__ dst, const int* __restrict__ src,
    const float* __restrict__ ea,
    const int* __restrict__ basep, int* __restrict__ fill,
    unsigned short* __restrict__ srcdst, unsigned short* __restrict__ eadst)
{
    int e = blockIdx.x * blockDim.x + threadIdx.x;
    if (e < N_EDGES) {
        const int d = dst[e];
        const int slot = atomicAdd(&fill[d], 1);
        const size_t pos = (size_t)basep[d] + slot;
        srcdst[pos] = (unsigned short)src[e];
        const float4* ap = (const float4*)(ea + (size_t)e * 16);
        const float4 a0 = ap[0], a1 = ap[1], a2 = ap[2], a3 = ap[3];
        short8v o0, o1;
        o0[0] = f2bf(a0.x); o0[1] = f2bf(a0.y); o0[2] = f2bf(a0.z); o0[3] = f2bf(a0.w);
        o0[4] = f2bf(a1.x); o0[5] = f2bf(a1.y); o0[6] = f2bf(a1.z); o0[7] = f2bf(a1.w);
        o1[0] = f2bf(a2.x); o1[1] = f2bf(a2.y); o1[2] = f2bf(a2.z); o1[3] = f2bf(a2.w);
        o1[4] = f2bf(a3.x); o1[5] = f2bf(a3.y); o1[6] = f2bf(a3.z); o1[7] = f2bf(a3.w);
        ((short8v*)eadst)[2 * pos]     = o0;
        ((short8v*)eadst)[2 * pos + 1] = o1;
    }
}

// ======================= shared prep kernels =======================
// fp32 [N][D] -> permuted bf16. One thread per output uint (pair).
template <int DIN>
__global__ __launch_bounds__(256) void cvt_perm_kernel(
    const float* __restrict__ in, unsigned int* __restrict__ out, int total)
{
    int t = blockIdx.x * blockDim.x + threadIdx.x;
    if (t < total) {
        const int m2 = t % (DIN / 2);
        const int n  = t / (DIN / 2);
        const int p  = m2 >> 4;
        const int c  = m2 & 15;
        const float lo = in[(size_t)n * DIN + 32 * p + c];
        const float hi = in[(size_t)n * DIN + 32 * p + 16 + c];
        out[t] = (unsigned int)(unsigned short)f2bf(lo) |
                 ((unsigned int)(unsigned short)f2bf(hi) << 16);
    }
}

// W[k][128] fp32 -> WT[d][K] bf16
template <int K>
__global__ __launch_bounds__(256) void cvtT_kernel(
    const float* __restrict__ W, unsigned short* __restrict__ WT)
{
    int t = blockIdx.x * blockDim.x + threadIdx.x;
    if (t < 128 * K) {
        const int d = t / K;
        const int k = t % K;
        WT[t] = (unsigned short)f2bf(W[k * 128 + d]);
    }
}

// fallback-path CSR (round-9)
__global__ __launch_bounds__(256) void fill_csr(
    const int* __restrict__ dst, const int* __restrict__ src,
    int* __restrict__ deg, int2* __restrict__ ecsr)
{
    int e = blockIdx.x * blockDim.x + threadIdx.x;
    if (e < N_EDGES) {
        int d = dst[e];
        int slot = atomicAdd(&deg[d], 1);
        if (slot < CAP) ecsr[d * CAP + slot] = make_int2(e, src[e]);
    }
}

// ======================= gather v7 (compact stream) =======================
template <int DIN>
__global__ __launch_bounds__(256, 8) void gather_v7(
    const unsigned short* __restrict__ hin,    // [N,DIN] bf16 permuted
    const unsigned short* __restrict__ srcdst, // [E] ushort
    const unsigned short* __restrict__ eadst,  // [E][16] bf16, dst-contiguous
    const int* __restrict__ deg,
    const int* __restrict__ basep,
    const float* __restrict__ We,              // [16,DIN] fp32
    const float* __restrict__ be,              // [DIN]
    unsigned short* __restrict__ hpre)         // [N,DIN] bf16 permuted out
{
    constexpr int NB = DIN / 16;
    constexpr int NP = DIN / 32;

    const int lane = threadIdx.x & 63;
    const int col = lane & 15;
    const int grp = lane >> 4;
    const int gwave = (blockIdx.x * blockDim.x + threadIdx.x) >> 6;
    const int nwaves = (gridDim.x * blockDim.x) >> 6;

    // B fragments: We rows k=grp*8+j (grp<2); bias row at k=16 (grp2, j=0)
    short8v Bf[NB];
#pragma unroll
    for (int b = 0; b < NB; ++b) {
        short8v f = {};
        if (grp < 2) {
#pragma unroll
            for (int j = 0; j < 8; ++j)
                f[j] = f2bf(We[(grp * 8 + j) * DIN + b * 16 + col]);
        } else if (grp == 2) {
            f[0] = f2bf(be[b * 16 + col]);
        }
        Bf[b] = f;
    }

    for (int n = gwave; n < N_NODES; n += nwaves) {
        const int dgc = deg[n];
        const int nch = (dgc + 15) >> 4;
        const int b0 = basep[n];

        float accv[NB];
#pragma unroll
        for (int b = 0; b < NB; ++b) accv[b] = 0.0f;

        for (int c = 0; c < nch; ++c) {
            const int pos0 = b0 + 16 * c;
            const int vcc = min(dgc - 16 * c, 16);   // valid edges (1..16)

            // lanes 0..vcc-1: src id (2B each, contiguous)
            int s_l = 0;
            if (lane < vcc) s_l = srcdst[pos0 + lane];

            // A fragment: lane col's edge row, SEQUENTIAL 32B records
            short8v Af = {};
            if (grp < 2) {
                if (col < vcc)
                    Af = *(const short8v*)(eadst + (size_t)(pos0 + col) * 16 + grp * 8);
            } else if (grp == 2) {
                Af[0] = (short)0x3F80;   // bf16 1.0 -> bias row
            }

            // src ids for this lane's 4 output rows (edges 4*grp+r)
            int sid[4];
#pragma unroll
            for (int r = 0; r < 4; ++r) sid[r] = __shfl(s_l, 4 * grp + r);

#pragma unroll
            for (int p = 0; p < NP; ++p) {
                const f32x4 zero = {0.0f, 0.0f, 0.0f, 0.0f};
                f32x4 lin0 = __builtin_amdgcn_mfma_f32_16x16x32_bf16(Af, Bf[2 * p], zero, 0, 0, 0);
                f32x4 lin1 = __builtin_amdgcn_mfma_f32_16x16x32_bf16(Af, Bf[2 * p + 1], zero, 0, 0, 0);
                float part0 = 0.0f, part1 = 0.0f;
#pragma unroll
                for (int r = 0; r < 4; ++r) {
                    if (4 * grp + r < vcc) {
                        const unsigned int u = *(const unsigned int*)
                            (hin + (size_t)sid[r] * DIN + 32 * p + 2 * col);
                        const float xlo = bf2f((unsigned short)(u & 0xffffu));
                        const float xhi = bf2f((unsigned short)(u >> 16));
                        part0 += fmaxf(xlo + lin0[r], 0.0f);
                        part1 += fmaxf(xhi + lin1[r], 0.0f);
                    }
                }
                accv[2 * p]     += part0;   // deferred cross-lane reduce
                accv[2 * p + 1] += part1;
            }
        }

        // reduce across lane groups once per node
#pragma unroll
        for (int b = 0; b < NB; ++b) {
            accv[b] += __shfl_xor(accv[b], 16);
            accv[b] += __shfl_xor(accv[b], 32);
        }

        // self term + store (fused h = x + agg), permuted bf16 out
        if (lane < 16) {
#pragma unroll
            for (int p = 0; p < NP; ++p) {
                const unsigned int u = *(const unsigned int*)
                    (hin + (size_t)n * DIN + 32 * p + 2 * lane);
                const float lo = bf2f((unsigned short)(u & 0xffffu)) + accv[2 * p];
                const float hi = bf2f((unsigned short)(u >> 16)) + accv[2 * p + 1];
                *(unsigned int*)(hpre + (size_t)n * DIN + 32 * p + 2 * lane) =
                    (unsigned int)(unsigned short)f2bf(lo) |
                    ((unsigned int)(unsigned short)f2bf(hi) << 16);
            }
        }
    }
}

// ======================= gather v6 (fallback, round-9) =======================
template <int DIN>
__global__ __launch_bounds__(256, 8) void gather_v6(
    const unsigned short* __restrict__ hin,
    const float* __restrict__ ea,
    const int* __restrict__ deg,
    const int2* __restrict__ ecsr,
    const float* __restrict__ We,
    const float* __restrict__ be,
    unsigned short* __restrict__ hpre)
{
    constexpr int NB = DIN / 16;
    constexpr int NP = DIN / 32;

    const int lane = threadIdx.x & 63;
    const int col = lane & 15;
    const int grp = lane >> 4;
    const int gwave = (blockIdx.x * blockDim.x + threadIdx.x) >> 6;
    const int nwaves = (gridDim.x * blockDim.x) >> 6;

    short8v Bf[NB];
#pragma unroll
    for (int b = 0; b < NB; ++b) {
        short8v f = {};
        if (grp < 2) {
#pragma unroll
            for (int j = 0; j < 8; ++j)
                f[j] = f2bf(We[(grp * 8 + j) * DIN + b * 16 + col]);
        } else if (grp == 2) {
            f[0] = f2bf(be[b * 16 + col]);
        }
        Bf[b] = f;
    }

    for (int n = gwave; n < N_NODES; n += nwaves) {
        const int dgc = min(deg[n], CAP);
        const int nch = (dgc + 15) >> 4;

        float accv[NB];
#pragma unroll
        for (int b = 0; b < NB; ++b) accv[b] = 0.0f;

        for (int c = 0; c < nch; ++c) {
            const int base = n * CAP + c * 16;
            const int vc = dgc - c * 16;

            int e_l = 0, s_l = 0;
            if (lane < vc) {
                const int2 pr = ecsr[base + lane];
                e_l = pr.x;
                s_l = pr.y;
            }

            const int e_col = __shfl(e_l, col);
            short8v Af = {};
            if (grp < 2) {
                if (col < vc) {
                    const float* ap = ea + (size_t)e_col * 16 + grp * 8;
                    const float4 a0 = *(const float4*)(ap);
                    const float4 a1 = *(const float4*)(ap + 4);
                    Af[0] = f2bf(a0.x); Af[1] = f2bf(a0.y);
                    Af[2] = f2bf(a0.z); Af[3] = f2bf(a0.w);
                    Af[4] = f2bf(a1.x); Af[5] = f2bf(a1.y);
                    Af[6] = f2bf(a1.z); Af[7] = f2bf(a1.w);
                }
            } else if (grp == 2) {
                Af[0] = (short)0x3F80;
            }

            int sid[4];
#pragma unroll
            for (int r = 0; r < 4; ++r) sid[r] = __shfl(s_l, 4 * grp + r);

#pragma unroll
            for (int p = 0; p < NP; ++p) {
                const f32x4 zero = {0.0f, 0.0f, 0.0f, 0.0f};
                f32x4 lin0 = __builtin_amdgcn_mfma_f32_16x16x32_bf16(Af, Bf[2 * p], zero, 0, 0, 0);
                f32x4 lin1 = __builtin_amdgcn_mfma_f32_16x16x32_bf16(Af, Bf[2 * p + 1], zero, 0, 0, 0);
                float part0 = 0.0f, part1 = 0.0f;
#pragma unroll
                for (int r = 0; r < 4; ++r) {
                    if (4 * grp + r < vc) {
                        const unsigned int u = *(const unsigned int*)
                            (hin + (size_t)sid[r] * DIN + 32 * p + 2 * col);
                        const float xlo = bf2f((unsigned short)(u & 0xffffu));
                        const float xhi = bf2f((unsigned short)(u >> 16));
                        part0 += fmaxf(xlo + lin0[r], 0.0f);
                        part1 += fmaxf(xhi + lin1[r], 0.0f);
                    }
                }
                accv[2 * p]     += part0;
                accv[2 * p + 1] += part1;
            }
        }

#pragma unroll
        for (int b = 0; b < NB; ++b) {
            accv[b] += __shfl_xor(accv[b], 16);
            accv[b] += __shfl_xor(accv[b], 32);
        }

        if (lane < 16) {
#pragma unroll
            for (int p = 0; p < NP; ++p) {
                const unsigned int u = *(const unsigned int*)
                    (hin + (size_t)n * DIN + 32 * p + 2 * lane);
                const float lo = bf2f((unsigned short)(u & 0xffffu)) + accv[2 * p];
                const float hi = bf2f((unsigned short)(u >> 16)) + accv[2 * p + 1];
                *(unsigned int*)(hpre + (size_t)n * DIN + 32 * p + 2 * lane) =
                    (unsigned int)(unsigned short)f2bf(lo) |
                    ((unsigned int)(unsigned short)f2bf(hi) << 16);
            }
        }
    }
}

// ======================= MFMA GIN MLP (round-9, proven) =======================
template <int DIN, int MODE>
__global__ __launch_bounds__(256) void mlp_mfma(
    const unsigned short* __restrict__ hpre,  // [N,DIN] bf16 permuted
    const unsigned short* __restrict__ WaT,   // [128][DIN] bf16
    const float* __restrict__ ba,
    const unsigned short* __restrict__ WbT,   // [128][128] bf16
    const float* __restrict__ bb,
    unsigned short* __restrict__ h1out,       // MODE 0 (permuted)
    const int* __restrict__ batch,            // MODE 1
    float* __restrict__ pooled)               // MODE 1 (pre-zeroed)
{
    constexpr int KS1 = DIN / 32;
    __shared__ unsigned short hls[32][DIN + 8];
    __shared__ unsigned short uls[32][128 + 8];
    __shared__ float vls[(MODE == 1) ? 32 : 1][(MODE == 1) ? 132 : 1];

    const int n0 = blockIdx.x * 32;
    const int tid = threadIdx.x;

    for (int f = tid * 4; f < 32 * DIN; f += 1024) {
        const int row = f / DIN, colc = f % DIN;
        const int n = n0 + row;
        ushort4 u = make_ushort4(0, 0, 0, 0);
        if (n < N_NODES) u = *(const ushort4*)(hpre + (size_t)n * DIN + colc);
        const int p = colc >> 5;
        const int q = (colc & 31) >> 2;
        hls[row][32 * p + 2 * q]          = u.x;
        hls[row][32 * p + 16 + 2 * q]     = u.y;
        hls[row][32 * p + 2 * q + 1]      = u.z;
        hls[row][32 * p + 16 + 2 * q + 1] = u.w;
    }
    __syncthreads();

    const int lane = tid & 63;
    const int w = tid >> 6;
    const int col = lane & 15;
    const int grp = lane >> 4;

    f32x4 acc00 = {0,0,0,0}, acc01 = {0,0,0,0}, acc10 = {0,0,0,0}, acc11 = {0,0,0,0};
#pragma unroll
    for (int ks = 0; ks < KS1; ++ks) {
        const short8v A0 = *(const short8v*)&hls[col][ks * 32 + grp * 8];
        const short8v A1 = *(const short8v*)&hls[16 + col][ks * 32 + grp * 8];
        const short8v B0 = *(const short8v*)&WaT[(size_t)(2 * w * 16 + col) * DIN + ks * 32 + grp * 8];
        const short8v B1 = *(const short8v*)&WaT[(size_t)((2 * w + 1) * 16 + col) * DIN + ks * 32 + grp * 8];
        acc00 = __builtin_amdgcn_mfma_f32_16x16x32_bf16(A0, B0, acc00, 0, 0, 0);
        acc01 = __builtin_amdgcn_mfma_f32_16x16x32_bf16(A0, B1, acc01, 0, 0, 0);
        acc10 = __builtin_amdgcn_mfma_f32_16x16x32_bf16(A1, B0, acc10, 0, 0, 0);
        acc11 = __builtin_amdgcn_mfma_f32_16x16x32_bf16(A1, B1, acc11, 0, 0, 0);
    }
    const float ba0 = ba[2 * w * 16 + col];
    const float ba1 = ba[(2 * w + 1) * 16 + col];
#pragma unroll
    for (int i = 0; i < 4; ++i) {
        const int r0 = grp * 4 + i;
        uls[r0][2 * w * 16 + col]            = (unsigned short)f2bf(fmaxf(acc00[i] + ba0, 0.f));
        uls[r0][(2 * w + 1) * 16 + col]      = (unsigned short)f2bf(fmaxf(acc01[i] + ba1, 0.f));
        uls[16 + r0][2 * w * 16 + col]       = (unsigned short)f2bf(fmaxf(acc10[i] + ba0, 0.f));
        uls[16 + r0][(2 * w + 1) * 16 + col] = (unsigned short)f2bf(fmaxf(acc11[i] + ba1, 0.f));
    }
    __syncthreads();

    acc00 = (f32x4){0,0,0,0}; acc01 = (f32x4){0,0,0,0};
    acc10 = (f32x4){0,0,0,0}; acc11 = (f32x4){0,0,0,0};
#pragma unroll
    for (int ks = 0; ks < 4; ++ks) {
        const short8v A0 = *(const short8v*)&uls[col][ks * 32 + grp * 8];
        const short8v A1 = *(const short8v*)&uls[16 + col][ks * 32 + grp * 8];
        const short8v B0 = *(const short8v*)&WbT[(size_t)(2 * w * 16 + col) * 128 + ks * 32 + grp * 8];
        const short8v B1 = *(const short8v*)&WbT[(size_t)((2 * w + 1) * 16 + col) * 128 + ks * 32 + grp * 8];
        acc00 = __builtin_amdgcn_mfma_f32_16x16x32_bf16(A0, B0, acc00, 0, 0, 0);
        acc01 = __builtin_amdgcn_mfma_f32_16x16x32_bf16(A0, B1, acc01, 0, 0, 0);
        acc10 = __builtin_amdgcn_mfma_f32_16x16x32_bf16(A1, B0, acc10, 0, 0, 0);
        acc11 = __builtin_amdgcn_mfma_f32_16x16x32_bf16(A1, B1, acc11, 0, 0, 0);
    }
    const float bb0 = bb[2 * w * 16 + col];
    const float bb1 = bb[(2 * w + 1) * 16 + col];

    if (MODE == 0) {
#pragma unroll
        for (int i = 0; i < 4; ++i) {
            const int nA = n0 + grp * 4 + i;
            if (nA < N_NODES) {
                const float v0 = fmaxf(acc00[i] + bb0, 0.f);
                const float v1 = fmaxf(acc01[i] + bb1, 0.f);
                *(unsigned int*)(h1out + (size_t)nA * 128 + 32 * w + 2 * col) =
                    (unsigned int)(unsigned short)f2bf(v0) |
                    ((unsigned int)(unsigned short)f2bf(v1) << 16);
            }
            const int nB = n0 + 16 + grp * 4 + i;
            if (nB < N_NODES) {
                const float v0 = fmaxf(acc10[i] + bb0, 0.f);
                const float v1 = fmaxf(acc11[i] + bb1, 0.f);
                *(unsigned int*)(h1out + (size_t)nB * 128 + 32 * w + 2 * col) =
                    (unsigned int)(unsigned short)f2bf(v0) |
                    ((unsigned int)(unsigned short)f2bf(v1) << 16);
            }
        }
    } else {
#pragma unroll
        for (int i = 0; i < 4; ++i) {
            const int r0 = grp * 4 + i;
            vls[r0][2 * w * 16 + col]            = fmaxf(acc00[i] + bb0, 0.f);
            vls[r0][(2 * w + 1) * 16 + col]      = fmaxf(acc01[i] + bb1, 0.f);
            vls[16 + r0][2 * w * 16 + col]       = fmaxf(acc10[i] + bb0, 0.f);
            vls[16 + r0][(2 * w + 1) * 16 + col] = fmaxf(acc11[i] + bb1, 0.f);
        }
        __syncthreads();
        if (tid < 128) {
            const int d = tid;
            const int lim = min(32, N_NODES - n0);
            float s = 0.0f;
            int bprev = -1;
            for (int q = 0; q < lim; ++q) {
                const int b = batch[n0 + q];
                if (b != bprev) {
                    if (bprev >= 0) atomicAdd(&pooled[bprev * 128 + d], s);
                    s = 0.0f;
                    bprev = b;
                }
                s += vls[q][d];
            }
            if (bprev >= 0) atomicAdd(&pooled[bprev * 128 + d], s);
        }
    }
}

// ---------------------------------------------------------------------------
// Final FC
// ---------------------------------------------------------------------------
__global__ __launch_bounds__(128) void fc_kernel(
    const float* __restrict__ pooled,
    const float* __restrict__ Wfc,
    const float* __restrict__ bfc,
    float* __restrict__ out)
{
    const int g = blockIdx.x;
    const int d = threadIdx.x;
    __shared__ float sp[128];
    sp[d] = pooled[g * 128 + d];
    __syncthreads();
    float acc = bfc[d];
    for (int k = 0; k < 128; ++k) acc = fmaf(sp[k], Wfc[k * 128 + d], acc);
    out[g * 128 + d] = acc;
}

extern "C" void kernel_launch(void* const* d_in, const int* in_sizes, int n_in,
                              void* d_out, int out_size, void* d_ws, size_t ws_size,
                              hipStream_t stream) {
    const float* x    = (const float*)d_in[0];
    const int*   eidx = (const int*)d_in[1];
    const float* ea   = (const float*)d_in[2];
    const int*   batch= (const int*)d_in[3];
    const float* We1  = (const float*)d_in[4];
    const float* be1  = (const float*)d_in[5];
    const float* W1a  = (const float*)d_in[6];
    const float* b1a  = (const float*)d_in[7];
    const float* W1b  = (const float*)d_in[8];
    const float* b1b  = (const float*)d_in[9];
    const float* We2  = (const float*)d_in[10];
    const float* be2  = (const float*)d_in[11];
    const float* W2a  = (const float*)d_in[12];
    const float* b2a  = (const float*)d_in[13];
    const float* W2b  = (const float*)d_in[14];
    const float* b2b  = (const float*)d_in[15];
    const float* Wfc  = (const float*)d_in[16];
    const float* bfc  = (const float*)d_in[17];
    float* out = (float*)d_out;

    const int* srcp = eidx;
    const int* dstp = eidx + N_EDGES;

    const int gblocks = 2048;
    const int mblocks = (N_NODES + 31) / 32;

    // ---- new-path layout (53.8 MB) ----
    {
        char* w = (char*)d_ws;
        unsigned short* bufA = (unsigned short*)w;  w += (size_t)N_NODES * 128 * 2;
        unsigned short* bufB = (unsigned short*)w;  w += (size_t)N_NODES * 128 * 2;
        int* deg   = (int*)w;                       w += (size_t)N_NODES * 4;
        int* basep = (int*)w;                       w += (size_t)N_NODES * 4;
        int* fillp = (int*)w;                       w += (size_t)N_NODES * 4;
        int* counter = (int*)w;                     w += 256;
        unsigned short* srcdst = (unsigned short*)w; w += (size_t)N_EDGES * 2;
        unsigned short* eadst = (unsigned short*)w;  w += (size_t)N_EDGES * 16 * 2;
        float* pooled = (float*)w;                  w += (size_t)N_GRAPHS * 128 * 4;
        unsigned short* W1aT = (unsigned short*)w;  w += (size_t)128 * 96 * 2;
        unsigned short* W1bT = (unsigned short*)w;  w += (size_t)128 * 128 * 2;
        unsigned short* W2aT = (unsigned short*)w;  w += (size_t)128 * 128 * 2;
        unsigned short* W2bT = (unsigned short*)w;  w += (size_t)128 * 128 * 2;
        const size_t need = (size_t)(w - (char*)d_ws);

        if (ws_size >= need) {
            // x16 lives in bufB (dead once mlp1 overwrites B with h1)
            unsigned short* x16 = bufB;

            // prep: compact CSR + conversions
            hipMemsetAsync(deg, 0, (size_t)N_NODES * 4, stream);
            hipMemsetAsync(fillp, 0, (size_t)N_NODES * 4, stream);
            hipMemsetAsync(counter, 0, 4, stream);
            count_deg<<<(N_EDGES + 255) / 256, 256, 0, stream>>>(dstp, deg);
            assign_base<<<(N_NODES + 255) / 256, 256, 0, stream>>>(deg, basep, counter);
            scatter_edges<<<(N_EDGES + 255) / 256, 256, 0, stream>>>(
                dstp, srcp, ea, basep, fillp, srcdst, eadst);
            {
                const int total = N_NODES * 96 / 2;
                cvt_perm_kernel<96><<<(total + 255) / 256, 256, 0, stream>>>(
                    x, (unsigned int*)x16, total);
            }
            cvtT_kernel<96><<<(128 * 96 + 255) / 256, 256, 0, stream>>>(W1a, W1aT);
            cvtT_kernel<128><<<(128 * 128 + 255) / 256, 256, 0, stream>>>(W1b, W1bT);
            cvtT_kernel<128><<<(128 * 128 + 255) / 256, 256, 0, stream>>>(W2a, W2aT);
            cvtT_kernel<128><<<(128 * 128 + 255) / 256, 256, 0, stream>>>(W2b, W2bT);

            // layer 1: x16(B) -> hpre(A); mlp1: A -> h1(B)
            gather_v7<96><<<gblocks, 256, 0, stream>>>(
                x16, srcdst, eadst, deg, basep, We1, be1, bufA);
            mlp_mfma<96, 0><<<mblocks, 256, 0, stream>>>(
                bufA, W1aT, b1a, W1bT, b1b, bufB, nullptr, nullptr);

            // layer 2: h1(B) -> hpre(A); mlp2: A -> pooled
            gather_v7<128><<<gblocks, 256, 0, stream>>>(
                bufB, srcdst, eadst, deg, basep, We2, be2, bufA);
            hipMemsetAsync(pooled, 0, (size_t)N_GRAPHS * 128 * 4, stream);
            mlp_mfma<128, 1><<<mblocks, 256, 0, stream>>>(
                bufA, W2aT, b2a, W2bT, b2b, nullptr, batch, pooled);

            fc_kernel<<<N_GRAPHS, 128, 0, stream>>>(pooled, Wfc, bfc, out);
            return;
        }
    }

    // ---- fallback: round-9 path (45.5 MB, proven) ----
    {
        char* w = (char*)d_ws;
        unsigned short* hpre = (unsigned short*)w;  w += (size_t)N_NODES * 128 * 2;
        unsigned short* h1 = (unsigned short*)w;    w += (size_t)N_NODES * 128 * 2;
        int* deg  = (int*)w;                        w += (size_t)N_NODES * 4;
        int2* ecsr = (int2*)w;                      w += (size_t)N_NODES * CAP * 8;
        float* pooled = (float*)w;                  w += (size_t)N_GRAPHS * 128 * 4;
        unsigned short* W1aT = (unsigned short*)w;  w += (size_t)128 * 96 * 2;
        unsigned short* W1bT = (unsigned short*)w;  w += (size_t)128 * 128 * 2;
        unsigned short* W2aT = (unsigned short*)w;  w += (size_t)128 * 128 * 2;
        unsigned short* W2bT = (unsigned short*)w;  w += (size_t)128 * 128 * 2;

        unsigned short* x16 = h1;

        hipMemsetAsync(deg, 0, (size_t)N_NODES * 4, stream);
        fill_csr<<<(N_EDGES + 255) / 256, 256, 0, stream>>>(dstp, srcp, deg, ecsr);
        {
            const int total = N_NODES * 96 / 2;
            cvt_perm_kernel<96><<<(total + 255) / 256, 256, 0, stream>>>(
                x, (unsigned int*)x16, total);
        }
        cvtT_kernel<96><<<(128 * 96 + 255) / 256, 256, 0, stream>>>(W1a, W1aT);
        cvtT_kernel<128><<<(128 * 128 + 255) / 256, 256, 0, stream>>>(W1b, W1bT);
        cvtT_kernel<128><<<(128 * 128 + 255) / 256, 256, 0, stream>>>(W2a, W2aT);
        cvtT_kernel<128><<<(128 * 128 + 255) / 256, 256, 0, stream>>>(W2b, W2bT);

        gather_v6<96><<<gblocks, 256, 0, stream>>>(
            x16, ea, deg, ecsr, We1, be1, hpre);
        mlp_mfma<96, 0><<<mblocks, 256, 0, stream>>>(
            hpre, W1aT, b1a, W1bT, b1b, h1, nullptr, nullptr);

        gather_v6<128><<<gblocks, 256, 0, stream>>>(
            h1, ea, deg, ecsr, We2, be2, hpre);
        hipMemsetAsync(pooled, 0, (size_t)N_GRAPHS * 128 * 4, stream);
        mlp_mfma<128, 1><<<mblocks, 256, 0, stream>>>(
            hpre, W2aT, b2a, W2bT, b2b, nullptr, batch, pooled);

        fc_kernel<<<N_GRAPHS, 128, 0, stream>>>(pooled, Wfc, bfc, out);
    }
}

// Round 11
// 369.418 us; speedup vs baseline: 1.2941x; 1.0012x over previous
//
#include <hip/hip_runtime.h>
#include <hip/hip_bf16.h>

#define N_NODES 50000
#define N_EDGES 800000
#define N_GRAPHS 512

typedef __attribute__((ext_vector_type(8))) short short8v;   // 8 bf16
typedef __attribute__((ext_vector_type(4))) float f32x4;

__device__ inline float bf2f(unsigned short u) {
    union { unsigned int i; float f; } v; v.i = ((unsigned int)u) << 16; return v.f;
}
__device__ inline short f2bf(float f) {
    __hip_bfloat16 h = __float2bfloat16(f);
    return *reinterpret_cast<short*>(&h);
}

// ---------------------------------------------------------------------------
// PERMUTED bf16 row layout (row of D dims, D%32==0):
//   memory position m = 32*p + 2*c + half  <->  dim d = 32*p + 16*half + c
// uint at index 16p+c in a row = dims (32p+c, 32p+16+c) = (block 2p, block 2p+1) col c
// ---------------------------------------------------------------------------

// ======================= CSR prep =======================
__global__ __launch_bounds__(256) void count_deg(
    const int* __restrict__ dst, int* __restrict__ deg)
{
    int e = blockIdx.x * blockDim.x + threadIdx.x;
    if (e < N_EDGES) atomicAdd(&deg[dst[e]], 1);
}

__global__ __launch_bounds__(256) void assign_base(
    const int* __restrict__ deg, int* __restrict__ basep, int* __restrict__ counter)
{
    int n = blockIdx.x * blockDim.x + threadIdx.x;
    if (n < N_NODES) basep[n] = atomicAdd(counter, deg[n]);
}

// scatter edges into dst-contiguous stream: srcdst (ushort) + eadst (bf16 row)
__global__ __launch_bounds__(256) void scatter_edges(
    const int* __restrict__ dst, const int* __restrict__ src,
    const float* __restrict__ ea,
    const int* __restrict__ basep, int* __restrict__ fill,
    unsigned short* __restrict__ srcdst, unsigned short* __restrict__ eadst)
{
    int e = blockIdx.x * blockDim.x + threadIdx.x;
    if (e < N_EDGES) {
        const int d = dst[e];
        const int slot = atomicAdd(&fill[d], 1);
        const size_t pos = (size_t)basep[d] + slot;
        srcdst[pos] = (unsigned short)src[e];
        const float4* ap = (const float4*)(ea + (size_t)e * 16);
        const float4 a0 = ap[0], a1 = ap[1], a2 = ap[2], a3 = ap[3];
        short8v o0, o1;
        o0[0] = f2bf(a0.x); o0[1] = f2bf(a0.y); o0[2] = f2bf(a0.z); o0[3] = f2bf(a0.w);
        o0[4] = f2bf(a1.x); o0[5] = f2bf(a1.y); o0[6] = f2bf(a1.z); o0[7] = f2bf(a1.w);
        o1[0] = f2bf(a2.x); o1[1] = f2bf(a2.y); o1[2] = f2bf(a2.z); o1[3] = f2bf(a2.w);
        o1[4] = f2bf(a3.x); o1[5] = f2bf(a3.y); o1[6] = f2bf(a3.z); o1[7] = f2bf(a3.w);
        ((short8v*)eadst)[2 * pos]     = o0;
        ((short8v*)eadst)[2 * pos + 1] = o1;
    }
}

// ======================= merged conversions (1 dispatch) =======================
// [0, T0):            x fp32 [N][96] -> permuted bf16 uints
// [T0, +128*96):      W1aT[d][96]  = bf16(W1a[k][d])
// then three 128x128: W1bT, W2aT, W2bT
#define T0_CVT (N_NODES * 48)
__global__ __launch_bounds__(256) void prep_convert(
    const float* __restrict__ x,
    const float* __restrict__ W1a, const float* __restrict__ W1b,
    const float* __restrict__ W2a, const float* __restrict__ W2b,
    unsigned int* __restrict__ x16,
    unsigned short* __restrict__ W1aT, unsigned short* __restrict__ W1bT,
    unsigned short* __restrict__ W2aT, unsigned short* __restrict__ W2bT)
{
    int t = blockIdx.x * blockDim.x + threadIdx.x;
    if (t < T0_CVT) {
        const int m2 = t % 48;
        const int n  = t / 48;
        const int p  = m2 >> 4;
        const int c  = m2 & 15;
        const float lo = x[(size_t)n * 96 + 32 * p + c];
        const float hi = x[(size_t)n * 96 + 32 * p + 16 + c];
        x16[t] = (unsigned int)(unsigned short)f2bf(lo) |
                 ((unsigned int)(unsigned short)f2bf(hi) << 16);
        return;
    }
    int u = t - T0_CVT;
    if (u < 128 * 96) {
        W1aT[u] = (unsigned short)f2bf(W1a[(u % 96) * 128 + u / 96]);
        return;
    }
    u -= 128 * 96;
    if (u < 16384) { W1bT[u] = (unsigned short)f2bf(W1b[(u & 127) * 128 + (u >> 7)]); return; }
    u -= 16384;
    if (u < 16384) { W2aT[u] = (unsigned short)f2bf(W2a[(u & 127) * 128 + (u >> 7)]); return; }
    u -= 16384;
    if (u < 16384) { W2bT[u] = (unsigned short)f2bf(W2b[(u & 127) * 128 + (u >> 7)]); }
}

// ======================= gather v8 (full-wave row I/O) =======================
template <int DIN>
__global__ __launch_bounds__(256, 8) void gather_v8(
    const unsigned short* __restrict__ hin,    // [N,DIN] bf16 permuted
    const unsigned short* __restrict__ srcdst, // [E] ushort
    const unsigned short* __restrict__ eadst,  // [E][16] bf16, dst-contiguous
    const int* __restrict__ deg,
    const int* __restrict__ basep,
    const float* __restrict__ We,              // [16,DIN] fp32
    const float* __restrict__ be,              // [DIN]
    unsigned short* __restrict__ hpre)         // [N,DIN] bf16 permuted out
{
    constexpr int NB = DIN / 16;
    constexpr int NP = DIN / 32;

    const int lane = threadIdx.x & 63;
    const int col = lane & 15;
    const int grp = lane >> 4;
    const int gwave = (blockIdx.x * blockDim.x + threadIdx.x) >> 6;
    const int nwaves = (gridDim.x * blockDim.x) >> 6;

    // B fragments: We rows k=grp*8+j (grp<2); bias row at k=16 (grp2, j=0)
    short8v Bf[NB];
#pragma unroll
    for (int b = 0; b < NB; ++b) {
        short8v f = {};
        if (grp < 2) {
#pragma unroll
            for (int j = 0; j < 8; ++j)
                f[j] = f2bf(We[(grp * 8 + j) * DIN + b * 16 + col]);
        } else if (grp == 2) {
            f[0] = f2bf(be[b * 16 + col]);
        }
        Bf[b] = f;
    }

    for (int n = gwave; n < N_NODES; n += nwaves) {
        const int dgc = deg[n];
        const int nch = (dgc + 15) >> 4;
        const int b0 = basep[n];

        float accv[NB];
#pragma unroll
        for (int b = 0; b < NB; ++b) accv[b] = 0.0f;

        for (int c = 0; c < nch; ++c) {
            const int pos0 = b0 + 16 * c;
            const int vcc = min(dgc - 16 * c, 16);   // valid edges (1..16)

            int s_l = 0;
            if (lane < vcc) s_l = srcdst[pos0 + lane];

            // A fragment: lane col's edge row, SEQUENTIAL 32B records
            short8v Af = {};
            if (grp < 2) {
                if (col < vcc)
                    Af = *(const short8v*)(eadst + (size_t)(pos0 + col) * 16 + grp * 8);
            } else if (grp == 2) {
                Af[0] = (short)0x3F80;   // bf16 1.0 -> bias row
            }

            int sid[4];
#pragma unroll
            for (int r = 0; r < 4; ++r) sid[r] = __shfl(s_l, 4 * grp + r);

#pragma unroll
            for (int p = 0; p < NP; ++p) {
                const f32x4 zero = {0.0f, 0.0f, 0.0f, 0.0f};
                f32x4 lin0 = __builtin_amdgcn_mfma_f32_16x16x32_bf16(Af, Bf[2 * p], zero, 0, 0, 0);
                f32x4 lin1 = __builtin_amdgcn_mfma_f32_16x16x32_bf16(Af, Bf[2 * p + 1], zero, 0, 0, 0);
                float part0 = 0.0f, part1 = 0.0f;
#pragma unroll
                for (int r = 0; r < 4; ++r) {
                    if (4 * grp + r < vcc) {
                        const unsigned int u = *(const unsigned int*)
                            (hin + (size_t)sid[r] * DIN + 32 * p + 2 * col);
                        const float xlo = bf2f((unsigned short)(u & 0xffffu));
                        const float xhi = bf2f((unsigned short)(u >> 16));
                        part0 += fmaxf(xlo + lin0[r], 0.0f);
                        part1 += fmaxf(xhi + lin1[r], 0.0f);
                    }
                }
                accv[2 * p]     += part0;   // deferred cross-lane reduce
                accv[2 * p + 1] += part1;
            }
        }

        // butterfly: after this ALL lanes hold the total for their own col
#pragma unroll
        for (int b = 0; b < NB; ++b) {
            accv[b] += __shfl_xor(accv[b], 16);
            accv[b] += __shfl_xor(accv[b], 32);
        }

        // redistribute so lane l owns row-uint l (pair-block p=l>>4, col=l&15),
        // then ONE full-wave self-load + ONE full-wave store (192/256B reqs).
        const float t0l = __shfl(accv[0], col), t0h = __shfl(accv[1], col);
        const float t1l = __shfl(accv[2], col), t1h = __shfl(accv[3], col);
        const float t2l = __shfl(accv[4], col), t2h = __shfl(accv[5], col);
        float lo, hi;
        if (DIN == 128) {
            const float t3l = __shfl(accv[NB - 2], col), t3h = __shfl(accv[NB - 1], col);
            lo = (grp == 0) ? t0l : (grp == 1) ? t1l : (grp == 2) ? t2l : t3l;
            hi = (grp == 0) ? t0h : (grp == 1) ? t1h : (grp == 2) ? t2h : t3h;
        } else {
            lo = (grp == 0) ? t0l : (grp == 1) ? t1l : t2l;
            hi = (grp == 0) ? t0h : (grp == 1) ? t1h : t2h;
        }

        if (lane < DIN / 2) {
            const unsigned int u =
                ((const unsigned int*)(hin + (size_t)n * DIN))[lane];
            const float slo = bf2f((unsigned short)(u & 0xffffu)) + lo;
            const float shi = bf2f((unsigned short)(u >> 16)) + hi;
            ((unsigned int*)(hpre + (size_t)n * DIN))[lane] =
                (unsigned int)(unsigned short)f2bf(slo) |
                ((unsigned int)(unsigned short)f2bf(shi) << 16);
        }
    }
}

// ======================= MFMA GIN MLP (proven) =======================
template <int DIN, int MODE>
__global__ __launch_bounds__(256) void mlp_mfma(
    const unsigned short* __restrict__ hpre,  // [N,DIN] bf16 permuted
    const unsigned short* __restrict__ WaT,   // [128][DIN] bf16
    const float* __restrict__ ba,
    const unsigned short* __restrict__ WbT,   // [128][128] bf16
    const float* __restrict__ bb,
    unsigned short* __restrict__ h1out,       // MODE 0 (permuted)
    const int* __restrict__ batch,            // MODE 1
    float* __restrict__ pooled)               // MODE 1 (pre-zeroed)
{
    constexpr int KS1 = DIN / 32;
    __shared__ unsigned short hls[32][DIN + 8];
    __shared__ unsigned short uls[32][128 + 8];
    __shared__ float vls[(MODE == 1) ? 32 : 1][(MODE == 1) ? 132 : 1];

    const int n0 = blockIdx.x * 32;
    const int tid = threadIdx.x;

    for (int f = tid * 4; f < 32 * DIN; f += 1024) {
        const int row = f / DIN, colc = f % DIN;
        const int n = n0 + row;
        ushort4 u = make_ushort4(0, 0, 0, 0);
        if (n < N_NODES) u = *(const ushort4*)(hpre + (size_t)n * DIN + colc);
        const int p = colc >> 5;
        const int q = (colc & 31) >> 2;
        hls[row][32 * p + 2 * q]          = u.x;
        hls[row][32 * p + 16 + 2 * q]     = u.y;
        hls[row][32 * p + 2 * q + 1]      = u.z;
        hls[row][32 * p + 16 + 2 * q + 1] = u.w;
    }
    __syncthreads();

    const int lane = tid & 63;
    const int w = tid >> 6;
    const int col = lane & 15;
    const int grp = lane >> 4;

    f32x4 acc00 = {0,0,0,0}, acc01 = {0,0,0,0}, acc10 = {0,0,0,0}, acc11 = {0,0,0,0};
#pragma unroll
    for (int ks = 0; ks < KS1; ++ks) {
        const short8v A0 = *(const short8v*)&hls[col][ks * 32 + grp * 8];
        const short8v A1 = *(const short8v*)&hls[16 + col][ks * 32 + grp * 8];
        const short8v B0 = *(const short8v*)&WaT[(size_t)(2 * w * 16 + col) * DIN + ks * 32 + grp * 8];
        const short8v B1 = *(const short8v*)&WaT[(size_t)((2 * w + 1) * 16 + col) * DIN + ks * 32 + grp * 8];
        acc00 = __builtin_amdgcn_mfma_f32_16x16x32_bf16(A0, B0, acc00, 0, 0, 0);
        acc01 = __builtin_amdgcn_mfma_f32_16x16x32_bf16(A0, B1, acc01, 0, 0, 0);
        acc10 = __builtin_amdgcn_mfma_f32_16x16x32_bf16(A1, B0, acc10, 0, 0, 0);
        acc11 = __builtin_amdgcn_mfma_f32_16x16x32_bf16(A1, B1, acc11, 0, 0, 0);
    }
    const float ba0 = ba[2 * w * 16 + col];
    const float ba1 = ba[(2 * w + 1) * 16 + col];
#pragma unroll
    for (int i = 0; i < 4; ++i) {
        const int r0 = grp * 4 + i;
        uls[r0][2 * w * 16 + col]            = (unsigned short)f2bf(fmaxf(acc00[i] + ba0, 0.f));
        uls[r0][(2 * w + 1) * 16 + col]      = (unsigned short)f2bf(fmaxf(acc01[i] + ba1, 0.f));
        uls[16 + r0][2 * w * 16 + col]       = (unsigned short)f2bf(fmaxf(acc10[i] + ba0, 0.f));
        uls[16 + r0][(2 * w + 1) * 16 + col] = (unsigned short)f2bf(fmaxf(acc11[i] + ba1, 0.f));
    }
    __syncthreads();

    acc00 = (f32x4){0,0,0,0}; acc01 = (f32x4){0,0,0,0};
    acc10 = (f32x4){0,0,0,0}; acc11 = (f32x4){0,0,0,0};
#pragma unroll
    for (int ks = 0; ks < 4; ++ks) {
        const short8v A0 = *(const short8v*)&uls[col][ks * 32 + grp * 8];
        const short8v A1 = *(const short8v*)&uls[16 + col][ks * 32 + grp * 8];
        const short8v B0 = *(const short8v*)&WbT[(size_t)(2 * w * 16 + col) * 128 + ks * 32 + grp * 8];
        const short8v B1 = *(const short8v*)&WbT[(size_t)((2 * w + 1) * 16 + col) * 128 + ks * 32 + grp * 8];
        acc00 = __builtin_amdgcn_mfma_f32_16x16x32_bf16(A0, B0, acc00, 0, 0, 0);
        acc01 = __builtin_amdgcn_mfma_f32_16x16x32_bf16(A0, B1, acc01, 0, 0, 0);
        acc10 = __builtin_amdgcn_mfma_f32_16x16x32_bf16(A1, B0, acc10, 0, 0, 0);
        acc11 = __builtin_amdgcn_mfma_f32_16x16x32_bf16(A1, B1, acc11, 0, 0, 0);
    }
    const float bb0 = bb[2 * w * 16 + col];
    const float bb1 = bb[(2 * w + 1) * 16 + col];

    if (MODE == 0) {
        // dims (32w+col, 32w+16+col) = the permute pair -> one uint store
#pragma unroll
        for (int i = 0; i < 4; ++i) {
            const int nA = n0 + grp * 4 + i;
            if (nA < N_NODES) {
                const float v0 = fmaxf(acc00[i] + bb0, 0.f);
                const float v1 = fmaxf(acc01[i] + bb1, 0.f);
                *(unsigned int*)(h1out + (size_t)nA * 128 + 32 * w + 2 * col) =
                    (unsigned int)(unsigned short)f2bf(v0) |
                    ((unsigned int)(unsigned short)f2bf(v1) << 16);
            }
            const int nB = n0 + 16 + grp * 4 + i;
            if (nB < N_NODES) {
                const float v0 = fmaxf(acc10[i] + bb0, 0.f);
                const float v1 = fmaxf(acc11[i] + bb1, 0.f);
                *(unsigned int*)(h1out + (size_t)nB * 128 + 32 * w + 2 * col) =
                    (unsigned int)(unsigned short)f2bf(v0) |
                    ((unsigned int)(unsigned short)f2bf(v1) << 16);
            }
        }
    } else {
#pragma unroll
        for (int i = 0; i < 4; ++i) {
            const int r0 = grp * 4 + i;
            vls[r0][2 * w * 16 + col]            = fmaxf(acc00[i] + bb0, 0.f);
            vls[r0][(2 * w + 1) * 16 + col]      = fmaxf(acc01[i] + bb1, 0.f);
            vls[16 + r0][2 * w * 16 + col]       = fmaxf(acc10[i] + bb0, 0.f);
            vls[16 + r0][(2 * w + 1) * 16 + col] = fmaxf(acc11[i] + bb1, 0.f);
        }
        __syncthreads();
        if (tid < 128) {
            const int d = tid;
            const int lim = min(32, N_NODES - n0);
            float s = 0.0f;
            int bprev = -1;
            for (int q = 0; q < lim; ++q) {
                const int b = batch[n0 + q];
                if (b != bprev) {
                    if (bprev >= 0) atomicAdd(&pooled[bprev * 128 + d], s);
                    s = 0.0f;
                    bprev = b;
                }
                s += vls[q][d];
            }
            if (bprev >= 0) atomicAdd(&pooled[bprev * 128 + d], s);
        }
    }
}

// ---------------------------------------------------------------------------
// Final FC
// ---------------------------------------------------------------------------
__global__ __launch_bounds__(128) void fc_kernel(
    const float* __restrict__ pooled,
    const float* __restrict__ Wfc,
    const float* __restrict__ bfc,
    float* __restrict__ out)
{
    const int g = blockIdx.x;
    const int d = threadIdx.x;
    __shared__ float sp[128];
    sp[d] = pooled[g * 128 + d];
    __syncthreads();
    float acc = bfc[d];
    for (int k = 0; k < 128; ++k) acc = fmaf(sp[k], Wfc[k * 128 + d], acc);
    out[g * 128 + d] = acc;
}

extern "C" void kernel_launch(void* const* d_in, const int* in_sizes, int n_in,
                              void* d_out, int out_size, void* d_ws, size_t ws_size,
                              hipStream_t stream) {
    const float* x    = (const float*)d_in[0];
    const int*   eidx = (const int*)d_in[1];
    const float* ea   = (const float*)d_in[2];
    const int*   batch= (const int*)d_in[3];
    const float* We1  = (const float*)d_in[4];
    const float* be1  = (const float*)d_in[5];
    const float* W1a  = (const float*)d_in[6];
    const float* b1a  = (const float*)d_in[7];
    const float* W1b  = (const float*)d_in[8];
    const float* b1b  = (const float*)d_in[9];
    const float* We2  = (const float*)d_in[10];
    const float* be2  = (const float*)d_in[11];
    const float* W2a  = (const float*)d_in[12];
    const float* b2a  = (const float*)d_in[13];
    const float* W2b  = (const float*)d_in[14];
    const float* b2b  = (const float*)d_in[15];
    const float* Wfc  = (const float*)d_in[16];
    const float* bfc  = (const float*)d_in[17];
    float* out = (float*)d_out;

    const int* srcp = eidx;
    const int* dstp = eidx + N_EDGES;

    const int gblocks = 2048;
    const int mblocks = (N_NODES + 31) / 32;

    // workspace layout (53.8 MB, proven to fit in round 10)
    char* w = (char*)d_ws;
    unsigned short* bufA = (unsigned short*)w;  w += (size_t)N_NODES * 128 * 2;
    unsigned short* bufB = (unsigned short*)w;  w += (size_t)N_NODES * 128 * 2;
    int* deg   = (int*)w;                       w += (size_t)N_NODES * 4;
    int* basep = (int*)w;                       w += (size_t)N_NODES * 4;
    int* fillp = (int*)w;                       w += (size_t)N_NODES * 4;
    int* counter = (int*)w;                     w += 256;
    unsigned short* srcdst = (unsigned short*)w; w += (size_t)N_EDGES * 2;
    unsigned short* eadst = (unsigned short*)w;  w += (size_t)N_EDGES * 16 * 2;
    float* pooled = (float*)w;                  w += (size_t)N_GRAPHS * 128 * 4;
    unsigned short* W1aT = (unsigned short*)w;  w += (size_t)128 * 96 * 2;
    unsigned short* W1bT = (unsigned short*)w;  w += (size_t)128 * 128 * 2;
    unsigned short* W2aT = (unsigned short*)w;  w += (size_t)128 * 128 * 2;
    unsigned short* W2bT = (unsigned short*)w;  w += (size_t)128 * 128 * 2;

    // x16 lives in bufB (dead once mlp1 overwrites bufB with h1)
    unsigned short* x16 = bufB;

    // ---- prep: compact CSR + merged conversions ----
    hipMemsetAsync(deg, 0, (size_t)N_NODES * 4, stream);
    hipMemsetAsync(fillp, 0, (size_t)N_NODES * 4, stream);
    hipMemsetAsync(counter, 0, 4, stream);
    count_deg<<<(N_EDGES + 255) / 256, 256, 0, stream>>>(dstp, deg);
    assign_base<<<(N_NODES + 255) / 256, 256, 0, stream>>>(deg, basep, counter);
    scatter_edges<<<(N_EDGES + 255) / 256, 256, 0, stream>>>(
        dstp, srcp, ea, basep, fillp, srcdst, eadst);
    {
        const int total = T0_CVT + 128 * 96 + 3 * 16384;
        prep_convert<<<(total + 255) / 256, 256, 0, stream>>>(
            x, W1a, W1b, W2a, W2b, (unsigned int*)x16, W1aT, W1bT, W2aT, W2bT);
    }

    // ---- layer 1: x16(B) -> hpre(A); mlp1: A -> h1(B) ----
    gather_v8<96><<<gblocks, 256, 0, stream>>>(
        x16, srcdst, eadst, deg, basep, We1, be1, bufA);
    mlp_mfma<96, 0><<<mblocks, 256, 0, stream>>>(
        bufA, W1aT, b1a, W1bT, b1b, bufB, nullptr, nullptr);

    // ---- layer 2: h1(B) -> hpre(A); mlp2: A -> pooled ----
    gather_v8<128><<<gblocks, 256, 0, stream>>>(
        bufB, srcdst, eadst, deg, basep, We2, be2, bufA);
    hipMemsetAsync(pooled, 0, (size_t)N_GRAPHS * 128 * 4, stream);
    mlp_mfma<128, 1><<<mblocks, 256, 0, stream>>>(
        bufA, W2aT, b2a, W2bT, b2b, nullptr, batch, pooled);

    // ---- readout ----
    fc_kernel<<<N_GRAPHS, 128, 0, stream>>>(pooled, Wfc, bfc, out);
}